// Round 4
// baseline (15366.211 us; speedup 1.0000x reference)
//
#include <hip/hip_runtime.h>

#define B_   1024
#define TE   168
#define TD   24
#define F_   64
#define H_   128
#define H2_  256
#define G_   512
#define KM_  320   // combined [h|c|x] K for m1

// ---- workspace float offsets ----
#define OFF_WMT    0          // [320][128]  rows 0..255 = We^T, 256..319 = Wi^T
#define OFF_VdT    40960      // [128][64]
#define OFF_eWihT  49152      // [64][512]
#define OFF_eWhhT  81920      // [128][512]
#define OFF_mWihT  147456     // [128][512]
#define OFF_mWhhT  212992     // [128][512]
#define OFF_WxT    278528     // [128][128]
#define OFF_WhT    294912     // [256][128]
#define OFF_dWihT  327680     // [128][512]
#define OFF_dWhhT  393216     // [128][512]
#define OFF_ENCB   458752     // [512] bih+bhh
#define OFF_MIDB   459264
#define OFF_DECB   459776
#define OFF_MID    460800                      // [1024][168][128]
#define OFF_WX     (OFF_MID + B_*TE*H_)        // [1024][168][128]
#define OFF_STH    (OFF_WX  + B_*TE*H_)        // [1024][128]
#define OFF_STC    (OFF_STH + B_*H_)
#define WS_FLOATS  (OFF_STC + B_*H_)

__device__ __forceinline__ float fexp2(float x) { return __builtin_amdgcn_exp2f(x); }
__device__ __forceinline__ float frcp(float x)  { return __builtin_amdgcn_rcpf(x); }
#define LOG2E 1.4426950408889634f

__device__ __forceinline__ float sigm(float x) {
    return frcp(1.f + fexp2(-LOG2E * x));
}
__device__ __forceinline__ float tanh_fast(float x) {
    float e = fexp2(2.f * LOG2E * x);
    return 1.f - 2.f * frcp(e + 1.f);
}

// Streaming GEMV slice with 8-deep float4 prefetch.
// Computes acc[0..3] += sum_k W[k][cg*4 .. cg*4+3] * act[k], K = nch*8.
// Wp = (float4*)W + cg  (stride = row length in float4s); act = LDS, 16B-aligned.
template<int STRIDE>
__device__ __forceinline__ void gemv_f4(const float4* __restrict__ Wp,
                                        const float* __restrict__ act, int nch,
                                        float& a0, float& a1, float& a2, float& a3) {
    const float4* a4 = (const float4*)act;
    float4 buf[8];
    #pragma unroll
    for (int u = 0; u < 8; ++u) buf[u] = Wp[u * STRIDE];
    for (int c = 0; c < nch - 1; ++c) {
        float4 h0 = a4[c * 2], h1 = a4[c * 2 + 1];
        #pragma unroll
        for (int u = 0; u < 8; ++u) {
            float4 w = buf[u];
            buf[u] = Wp[((c + 1) * 8 + u) * STRIDE];
            float hv = (u < 4) ? ((const float*)&h0)[u & 3] : ((const float*)&h1)[u & 3];
            a0 += w.x * hv; a1 += w.y * hv; a2 += w.z * hv; a3 += w.w * hv;
        }
    }
    {
        int c = nch - 1;
        float4 h0 = a4[c * 2], h1 = a4[c * 2 + 1];
        #pragma unroll
        for (int u = 0; u < 8; ++u) {
            float4 w = buf[u];
            float hv = (u < 4) ? ((const float*)&h0)[u & 3] : ((const float*)&h1)[u & 3];
            a0 += w.x * hv; a1 += w.y * hv; a2 += w.z * hv; a3 += w.w * hv;
        }
    }
}

// ---------------- prep: transpose weights to [K][N], sum bias pairs ----------------
struct PrepArgs {
    const float *We, *Wi, *Vd, *eWih, *eWhh, *eBih, *eBhh,
                *mWih, *mWhh, *mBih, *mBhh, *Wx, *Wh, *dWih, *dWhh, *dBih, *dBhh;
};

__global__ void prep_kernel(PrepArgs a, float* __restrict__ ws) {
    int sec  = blockIdx.x >> 2;
    int base = (blockIdx.x & 3) * blockDim.x + threadIdx.x;
    const int stride = blockDim.x * 4;
    const float* src = nullptr; int R = 0, C = 0, off = 0;
    switch (sec) {
        case 0:  src = a.We;   R = 128; C = 256; off = OFF_WMT;           break;
        case 1:  src = a.Wi;   R = 128; C = 64;  off = OFF_WMT + 32768;   break;
        case 2:  src = a.Vd;   R = 64;  C = 128; off = OFF_VdT;   break;
        case 3:  src = a.eWih; R = 512; C = 64;  off = OFF_eWihT; break;
        case 4:  src = a.eWhh; R = 512; C = 128; off = OFF_eWhhT; break;
        case 5:  src = a.mWih; R = 512; C = 128; off = OFF_mWihT; break;
        case 6:  src = a.mWhh; R = 512; C = 128; off = OFF_mWhhT; break;
        case 7:  src = a.Wx;   R = 128; C = 128; off = OFF_WxT;   break;
        case 8:  src = a.Wh;   R = 128; C = 256; off = OFF_WhT;   break;
        case 9:  src = a.dWih; R = 512; C = 128; off = OFF_dWihT; break;
        case 10: src = a.dWhh; R = 512; C = 128; off = OFF_dWhhT; break;
        case 11: for (int i = base; i < 512; i += stride) ws[OFF_ENCB + i] = a.eBih[i] + a.eBhh[i]; return;
        case 12: for (int i = base; i < 512; i += stride) ws[OFF_MIDB + i] = a.mBih[i] + a.mBhh[i]; return;
        case 13: for (int i = base; i < 512; i += stride) ws[OFF_DECB + i] = a.dBih[i] + a.dBhh[i]; return;
        default: return;
    }
    int n = R * C;
    int rmask  = R - 1;
    int rshift = (R == 512) ? 9 : ((R == 128) ? 7 : 6);
    for (int o = base; o < n; o += stride) {
        int r = o & rmask, c = o >> rshift;
        ws[off + o] = src[r * C + c];
    }
}

// ---------------- persistent encoder + mid LSTM: 256 blocks x 512 thr, 4 rows/block ----------------
__global__ __launch_bounds__(512, 1) void enc_mid_kernel(
    const float* __restrict__ x_all,   // [B][Te][F]
    const float* __restrict__ Wi_b,
    const float* __restrict__ Vd_b,
    const float* __restrict__ Wx_b,
    float* __restrict__ ws)
{
    __shared__ __align__(16) float hcx[4][KM_];     // [h | c | x] per row
    __shared__ __align__(16) float hm[4][H_];
    __shared__ __align__(16) float cm[4][H_];
    __shared__ __align__(16) float xin[4][F_];
    __shared__ __align__(16) float xnext[4][F_];
    __shared__ __align__(16) float av[4][H_];
    __shared__ __align__(16) float avp[4][4][H_];   // m1 k-split partials
    __shared__ __align__(16) float sp[8][4][F_];    // VdT k-split partials
    __shared__ __align__(16) float gt[4][G_];
    __shared__ __align__(16) float wxp[4][4][H_];
    __shared__ __align__(16) float bWi[H_], bVd[F_], bWx[H_];
    __shared__ __align__(16) float bE[G_], bM[G_];

    const int tid = threadIdx.x;
    const int b0  = blockIdx.x * 4;

    for (int i = tid; i < 4 * KM_; i += 512) { int r = i / KM_, c = i % KM_; hcx[r][c] = 0.f; }
    { ((float*)hm)[tid] = 0.f; ((float*)cm)[tid] = 0.f; }
    if (tid < H_) { bWi[tid] = Wi_b[tid]; bWx[tid] = Wx_b[tid]; }
    if (tid < F_) bVd[tid] = Vd_b[tid];
    bE[tid] = ws[OFF_ENCB + tid];
    bM[tid] = ws[OFF_MIDB + tid];
    if (tid < 256) { // x for t=0
        int r = tid >> 6, f = tid & 63;
        hcx[r][H2_ + f] = x_all[((b0 + r) * TE + 0) * F_ + f];
    }
    __syncthreads();

    const float4* WmT4   = (const float4*)(ws + OFF_WMT);     // [320][32] f4
    const float4* VdT4   = (const float4*)(ws + OFF_VdT);     // [128][16] f4
    const float4* eWihT4 = (const float4*)(ws + OFF_eWihT);   // [64][128] f4
    const float4* eWhhT4 = (const float4*)(ws + OFF_eWhhT);   // [128][128] f4
    const float4* mWihT4 = (const float4*)(ws + OFF_mWihT);   // [128][128] f4
    const float4* mWhhT4 = (const float4*)(ws + OFF_mWhhT);   // [128][128] f4
    const float4* WxT4   = (const float4*)(ws + OFF_WxT);     // [128][32] f4
    float* mid_out = ws + OFF_MID;
    float* wx_out  = ws + OFF_WX;

    for (int t = 0; t < TE; ++t) {
        // P1: m1 partials  avp[ks] = [h|c|x](k-slice) @ WmT   (k-split x4, 80 each)
        {
            int cg = tid & 31, r = (tid >> 5) & 3, ks = tid >> 7;
            int k0 = ks * 80;
            float a0 = 0.f, a1 = 0.f, a2 = 0.f, a3 = 0.f;
            gemv_f4<32>(WmT4 + k0 * 32 + cg, &hcx[r][k0], 10, a0, a1, a2, a3);
            *(float4*)&avp[ks][r][cg * 4] = make_float4(a0, a1, a2, a3);
        }
        __syncthreads();

        // P2: combine partials + bias + tanh -> av
        {
            int r = tid >> 7, j = tid & 127;
            float v = (avp[0][r][j] + avp[1][r][j]) + (avp[2][r][j] + avp[3][r][j]) + bWi[j];
            av[r][j] = tanh_fast(v);
        }
        __syncthreads();

        // P3a: s partials = av(k-slice)@VdT  (k-split x8, 16 each)
        {
            int cg = tid & 15, r = (tid >> 4) & 3, ks = tid >> 6;
            int k0 = ks * 16;
            float a0 = 0.f, a1 = 0.f, a2 = 0.f, a3 = 0.f;
            gemv_f4<16>(VdT4 + k0 * 16 + cg, &av[r][k0], 2, a0, a1, a2, a3);
            *(float4*)&sp[ks][r][cg * 4] = make_float4(a0, a1, a2, a3);
        }
        __syncthreads();

        // P3b: combine + softmax over 64 -> xin (waves 0-3); waves 4-7 load x_{t+1}
        if (tid < 256) {
            int j = tid & 63, r = tid >> 6;
            float acc = bVd[j] + (((sp[0][r][j] + sp[1][r][j]) + (sp[2][r][j] + sp[3][r][j]))
                               + ((sp[4][r][j] + sp[5][r][j]) + (sp[6][r][j] + sp[7][r][j])));
            float m = acc;
            for (int off = 32; off > 0; off >>= 1) m = fmaxf(m, __shfl_xor(m, off, 64));
            float e = fexp2((acc - m) * LOG2E);
            float ssum = e;
            for (int off = 32; off > 0; off >>= 1) ssum += __shfl_xor(ssum, off, 64);
            xin[r][j] = hcx[r][H2_ + j] * e * frcp(ssum);
        } else if (t + 1 < TE) {
            int q = tid - 256, r = q >> 6, f = q & 63;
            xnext[r][f] = x_all[((b0 + r) * TE + (t + 1)) * F_ + f];
        }
        __syncthreads();

        // P4: enc gates [4][512] = xin@eWihT + h@eWhhT + bE
        {
            int cg = tid & 127, r = tid >> 7;
            int j0 = cg * 4;
            float4 b = *(const float4*)&bE[j0];
            float a0 = b.x, a1 = b.y, a2 = b.z, a3 = b.w;
            gemv_f4<128>(eWihT4 + cg, xin[r], 8,  a0, a1, a2, a3);
            gemv_f4<128>(eWhhT4 + cg, hcx[r], 16, a0, a1, a2, a3);
            *(float4*)&gt[r][j0] = make_float4(a0, a1, a2, a3);
        }
        __syncthreads();

        // P5: enc LSTM cell; threads 0-255 also install prefetched x
        {
            int j = tid & 127, r = tid >> 7;
            float gi = gt[r][j], gf = gt[r][j+128], gg = gt[r][j+256], go = gt[r][j+384];
            float c = sigm(gf) * hcx[r][H_ + j] + sigm(gi) * tanh_fast(gg);
            float h = sigm(go) * tanh_fast(c);
            hcx[r][H_ + j] = c; hcx[r][j] = h;
            if (tid < 256 && t + 1 < TE) {
                int rr = tid >> 6, f = tid & 63;
                hcx[rr][H2_ + f] = xnext[rr][f];
            }
        }
        __syncthreads();

        // P6: mid gates [4][512] = h_enc@mWihT + h_mid@mWhhT + bM
        {
            int cg = tid & 127, r = tid >> 7;
            int j0 = cg * 4;
            float4 b = *(const float4*)&bM[j0];
            float a0 = b.x, a1 = b.y, a2 = b.z, a3 = b.w;
            gemv_f4<128>(mWihT4 + cg, hcx[r], 16, a0, a1, a2, a3);
            gemv_f4<128>(mWhhT4 + cg, hm[r],  16, a0, a1, a2, a3);
            *(float4*)&gt[r][j0] = make_float4(a0, a1, a2, a3);
        }
        __syncthreads();

        // P7: mid LSTM cell + store mid_out
        {
            int j = tid & 127, r = tid >> 7;
            float gi = gt[r][j], gf = gt[r][j+128], gg = gt[r][j+256], go = gt[r][j+384];
            float c = sigm(gf) * cm[r][j] + sigm(gi) * tanh_fast(gg);
            float h = sigm(go) * tanh_fast(c);
            cm[r][j] = c; hm[r][j] = h;
            mid_out[((b0 + r) * TE + t) * H_ + j] = h;
        }
        __syncthreads();

        // P8: wx partials (k-split x4, 32 each)
        {
            int cg = tid & 31, r = (tid >> 5) & 3, ks = tid >> 7;
            int k0 = ks * 32;
            float a0 = 0.f, a1 = 0.f, a2 = 0.f, a3 = 0.f;
            gemv_f4<32>(WxT4 + k0 * 32 + cg, &hm[r][k0], 4, a0, a1, a2, a3);
            *(float4*)&wxp[ks][r][cg * 4] = make_float4(a0, a1, a2, a3);
        }
        __syncthreads();

        // P8b: combine + global store, then straight into next P1 (no barrier needed:
        // next P1 writes avp [last read at P2] and reads hcx [stable since P5])
        {
            int j = tid & 127, r = tid >> 7;
            wx_out[((b0 + r) * TE + t) * H_ + j] =
                bWx[j] + (wxp[0][r][j] + wxp[1][r][j]) + (wxp[2][r][j] + wxp[3][r][j]);
        }
    }

    __syncthreads();
    {
        int j = tid & 127, r = tid >> 7;
        ws[OFF_STH + (b0 + r) * H_ + j] = hm[r][j];
        ws[OFF_STC + (b0 + r) * H_ + j] = cm[r][j];
    }
}

// ---------------- persistent decoder: 256 blocks x 512 thr, 4 rows/block ----------------
#define QP_ 136   // padded qv row stride: 16B-aligned, bank-offset 8 per row

__global__ __launch_bounds__(512, 1) void dec_kernel(
    const float* __restrict__ Vw_in,
    const float* __restrict__ Vb_in,
    const float* __restrict__ rw_in,
    const float* __restrict__ rb_in,
    const float* __restrict__ ws,
    float* __restrict__ out)
{
    __shared__ __align__(16) float hc2[4][H2_];      // [hi | ci]
    __shared__ __align__(16) float qv[4][QP_];       // q, then reused as dec_in
    __shared__ __align__(16) float qp[4][4][H_];     // q k-split partials
    __shared__ __align__(16) float sb[4][TE];
    __shared__ __align__(16) float dinp[4][4][H_];   // dec_in tp-split partials
    __shared__ __align__(16) float gt2[4][G_];
    __shared__ __align__(16) float bD[G_], Vw[H_], rw[H_];

    const int tid = threadIdx.x;
    const int b0  = blockIdx.x * 4;
    const float Vb = Vb_in[0], rb = rb_in[0];

    for (int i = tid; i < 4 * H2_; i += 512) {
        int r = i >> 8, c = i & 255;
        hc2[r][c] = (c < H_) ? ws[OFF_STH + (b0 + r) * H_ + c]
                             : ws[OFF_STC + (b0 + r) * H_ + (c - H_)];
    }
    if (tid < H_) { Vw[tid] = Vw_in[tid]; rw[tid] = rw_in[tid]; }
    bD[tid] = ws[OFF_DECB + tid];
    __syncthreads();

    const float4* WhT4   = (const float4*)(ws + OFF_WhT);     // [256][32] f4
    const float4* dWihT4 = (const float4*)(ws + OFF_dWihT);   // [128][128] f4
    const float4* dWhhT4 = (const float4*)(ws + OFF_dWhhT);   // [128][128] f4
    const float4* wx4    = (const float4*)(ws + OFF_WX);
    const float4* mid4   = (const float4*)(ws + OFF_MID);

    for (int td = 0; td < TD; ++td) {
        // P1: q partials = [hi|ci]@WhT  (k-split x4, 64 each)
        {
            int cg = tid & 31, r = (tid >> 5) & 3, ks = tid >> 7;
            int k0 = ks * 64;
            float a0 = 0.f, a1 = 0.f, a2 = 0.f, a3 = 0.f;
            gemv_f4<32>(WhT4 + k0 * 32 + cg, &hc2[r][k0], 8, a0, a1, a2, a3);
            *(float4*)&qp[ks][r][cg * 4] = make_float4(a0, a1, a2, a3);
        }
        __syncthreads();
        // P1b: combine
        {
            int j = tid & 127, r = tid >> 7;
            qv[r][j] = (qp[0][r][j] + qp[1][r][j]) + (qp[2][r][j] + qp[3][r][j]);
        }
        __syncthreads();

        // P2: scores sb[r][tp] = sum_h tanh(q[r][h] + wx[b][tp][h]) * Vw[h] + Vb
        for (int task = tid; task < 4 * TE; task += 512) {
            int r = task & 3, tp = task >> 2;
            const float4* wxr = wx4 + ((size_t)(b0 + r) * TE + tp) * (H_ / 4);
            float4 buf[4];
            #pragma unroll
            for (int u = 0; u < 4; ++u) buf[u] = wxr[u];
            float acc = Vb;
            for (int c = 0; c < 7; ++c) {
                #pragma unroll
                for (int u = 0; u < 4; ++u) {
                    float4 w = buf[u];
                    buf[u] = wxr[(c + 1) * 4 + u];
                    int j = (c * 4 + u) * 4;
                    float4 q = *(const float4*)&qv[r][j];
                    float4 v = *(const float4*)&Vw[j];
                    acc += tanh_fast(q.x + w.x) * v.x;
                    acc += tanh_fast(q.y + w.y) * v.y;
                    acc += tanh_fast(q.z + w.z) * v.z;
                    acc += tanh_fast(q.w + w.w) * v.w;
                }
            }
            #pragma unroll
            for (int u = 0; u < 4; ++u) {
                float4 w = buf[u];
                int j = (28 + u) * 4;
                float4 q = *(const float4*)&qv[r][j];
                float4 v = *(const float4*)&Vw[j];
                acc += tanh_fast(q.x + w.x) * v.x;
                acc += tanh_fast(q.y + w.y) * v.y;
                acc += tanh_fast(q.z + w.z) * v.z;
                acc += tanh_fast(q.w + w.w) * v.w;
            }
            sb[r][tp] = acc;
        }
        __syncthreads();

        // P3: dec_in partials over tp chunks of 42 (prefetch depth 7)
        {
            int ts = tid >> 7, r = (tid >> 5) & 3, cg = tid & 31;
            int t0 = ts * 42;
            const float4* mp = mid4 + ((size_t)(b0 + r) * TE + t0) * 32 + cg;
            float4 mb[7];
            #pragma unroll
            for (int u = 0; u < 7; ++u) mb[u] = mp[u * 32];
            float ax = 0.f, ay = 0.f, az = 0.f, aw = 0.f;
            for (int c = 0; c < 5; ++c) {
                #pragma unroll
                for (int u = 0; u < 7; ++u) {
                    float4 m = mb[u];
                    mb[u] = mp[((c + 1) * 7 + u) * 32];
                    float s = sb[r][t0 + c * 7 + u];
                    ax += s * m.x; ay += s * m.y; az += s * m.z; aw += s * m.w;
                }
            }
            #pragma unroll
            for (int u = 0; u < 7; ++u) {
                float4 m = mb[u];
                float s = sb[r][t0 + 35 + u];
                ax += s * m.x; ay += s * m.y; az += s * m.z; aw += s * m.w;
            }
            *(float4*)&dinp[ts][r][cg * 4] = make_float4(ax, ay, az, aw);
        }
        __syncthreads();
        // P3b: combine into qv (reused as dec_in)
        {
            int j = tid & 127, r = tid >> 7;
            qv[r][j] = (dinp[0][r][j] + dinp[1][r][j]) + (dinp[2][r][j] + dinp[3][r][j]);
        }
        __syncthreads();

        // P4: gates [4][512] = dec_in@dWihT + hi@dWhhT + bD
        {
            int cg = tid & 127, r = tid >> 7;
            int j0 = cg * 4;
            float4 b = *(const float4*)&bD[j0];
            float a0 = b.x, a1 = b.y, a2 = b.z, a3 = b.w;
            gemv_f4<128>(dWihT4 + cg, qv[r],  16, a0, a1, a2, a3);
            gemv_f4<128>(dWhhT4 + cg, hc2[r], 16, a0, a1, a2, a3);
            *(float4*)&gt2[r][j0] = make_float4(a0, a1, a2, a3);
        }
        __syncthreads();

        // P5: LSTM update
        {
            int j = tid & 127, r = tid >> 7;
            float gi = gt2[r][j], gf = gt2[r][j+128], gg = gt2[r][j+256], go = gt2[r][j+384];
            float c = sigm(gf) * hc2[r][H_ + j] + sigm(gi) * tanh_fast(gg);
            float h = sigm(go) * tanh_fast(c);
            hc2[r][H_ + j] = c; hc2[r][j] = h;
        }
        __syncthreads();

        // P6: out[b][td] = h . reg_w + reg_b  (no trailing barrier: next P1 writes qp,
        // last read at P1b; hc2 stable; both P6 and next P1 only read hc2)
        if (tid < 256) {
            int r = tid >> 6, lane = tid & 63;
            float v = hc2[r][lane] * rw[lane] + hc2[r][lane + 64] * rw[lane + 64];
            for (int off = 32; off > 0; off >>= 1) v += __shfl_xor(v, off, 64);
            if (lane == 0) out[(b0 + r) * TD + td] = v + rb;
        }
    }
}

extern "C" void kernel_launch(void* const* d_in, const int* in_sizes, int n_in,
                              void* d_out, int out_size, void* d_ws, size_t ws_size,
                              hipStream_t stream)
{
    (void)in_sizes; (void)n_in; (void)out_size;
    if (ws_size < (size_t)WS_FLOATS * sizeof(float)) return;

    const float* x_all = (const float*)d_in[0];
    const float* Wi_b  = (const float*)d_in[3];
    const float* Vd_b  = (const float*)d_in[6];
    const float* Wx_b  = (const float*)d_in[16];
    const float* V_w   = (const float*)d_in[18];
    const float* V_b   = (const float*)d_in[19];
    const float* reg_w = (const float*)d_in[24];
    const float* reg_b = (const float*)d_in[25];
    float* ws  = (float*)d_ws;
    float* out = (float*)d_out;

    PrepArgs pa{
        (const float*)d_in[4],  // We_w
        (const float*)d_in[2],  // Wi_w
        (const float*)d_in[5],  // Vd_w
        (const float*)d_in[7],  // enc_Wih
        (const float*)d_in[8],  // enc_Whh
        (const float*)d_in[9],  // enc_bih
        (const float*)d_in[10], // enc_bhh
        (const float*)d_in[11], // mid_Wih
        (const float*)d_in[12], // mid_Whh
        (const float*)d_in[13], // mid_bih
        (const float*)d_in[14], // mid_bhh
        (const float*)d_in[15], // Wx_w
        (const float*)d_in[17], // Wh_w
        (const float*)d_in[20], // dec_Wih
        (const float*)d_in[21], // dec_Whh
        (const float*)d_in[22], // dec_bih
        (const float*)d_in[23]  // dec_bhh
    };

    prep_kernel<<<56, 256, 0, stream>>>(pa, ws);
    enc_mid_kernel<<<256, 512, 0, stream>>>(x_all, Wi_b, Vd_b, Wx_b, ws);
    dec_kernel<<<256, 512, 0, stream>>>(V_w, V_b, reg_w, reg_b, ws, out);
}

// Round 5
// 10073.797 us; speedup vs baseline: 1.5254x; 1.5254x over previous
//
#include <hip/hip_runtime.h>

#define B_   1024
#define TE   168
#define TD   24
#define F_   64
#define H_   128
#define H2_  256
#define G_   512
#define KM_  320   // combined [h|c|x] K for m1

// ---- workspace float offsets ----
#define OFF_WMT    0          // [320][128]  rows 0..255 = We^T, 256..319 = Wi^T
#define OFF_VdT    40960      // [128][64]
#define OFF_eWihT  49152      // [64][512]
#define OFF_eWhhT  81920      // [128][512]
#define OFF_mWihT  147456     // [128][512]
#define OFF_mWhhT  212992     // [128][512]
#define OFF_WxT    278528     // [128][128]
#define OFF_WhT    294912     // [256][128]
#define OFF_dWihT  327680     // [128][512]
#define OFF_dWhhT  393216     // [128][512]
#define OFF_ENCB   458752     // [512] bih+bhh
#define OFF_MIDB   459264
#define OFF_DECB   459776
#define OFF_MID    460800                      // [1024][168][128]
#define OFF_WX     (OFF_MID + B_*TE*H_)        // [1024][168][128]
#define OFF_STH    (OFF_WX  + B_*TE*H_)        // [1024][128]
#define OFF_STC    (OFF_STH + B_*H_)
#define WS_FLOATS  (OFF_STC + B_*H_)

__device__ __forceinline__ float fexp2(float x) { return __builtin_amdgcn_exp2f(x); }
__device__ __forceinline__ float frcp(float x)  { return __builtin_amdgcn_rcpf(x); }
#define LOG2E 1.4426950408889634f

__device__ __forceinline__ float sigm(float x) {
    return frcp(1.f + fexp2(-LOG2E * x));
}
__device__ __forceinline__ float tanh_fast(float x) {
    float e = fexp2(2.f * LOG2E * x);
    return 1.f - 2.f * frcp(e + 1.f);
}

#define FMA4(g, w, s) { g.x += w.x*(s); g.y += w.y*(s); g.z += w.z*(s); g.w += w.w*(s); }

// ---------------- prep: transpose weights to [K][N], sum bias pairs ----------------
struct PrepArgs {
    const float *We, *Wi, *Vd, *eWih, *eWhh, *eBih, *eBhh,
                *mWih, *mWhh, *mBih, *mBhh, *Wx, *Wh, *dWih, *dWhh, *dBih, *dBhh;
};

__global__ void prep_kernel(PrepArgs a, float* __restrict__ ws) {
    int sec  = blockIdx.x >> 2;
    int base = (blockIdx.x & 3) * blockDim.x + threadIdx.x;
    const int stride = blockDim.x * 4;
    const float* src = nullptr; int R = 0, C = 0, off = 0;
    switch (sec) {
        case 0:  src = a.We;   R = 128; C = 256; off = OFF_WMT;           break;
        case 1:  src = a.Wi;   R = 128; C = 64;  off = OFF_WMT + 32768;   break;
        case 2:  src = a.Vd;   R = 64;  C = 128; off = OFF_VdT;   break;
        case 3:  src = a.eWih; R = 512; C = 64;  off = OFF_eWihT; break;
        case 4:  src = a.eWhh; R = 512; C = 128; off = OFF_eWhhT; break;
        case 5:  src = a.mWih; R = 512; C = 128; off = OFF_mWihT; break;
        case 6:  src = a.mWhh; R = 512; C = 128; off = OFF_mWhhT; break;
        case 7:  src = a.Wx;   R = 128; C = 128; off = OFF_WxT;   break;
        case 8:  src = a.Wh;   R = 128; C = 256; off = OFF_WhT;   break;
        case 9:  src = a.dWih; R = 512; C = 128; off = OFF_dWihT; break;
        case 10: src = a.dWhh; R = 512; C = 128; off = OFF_dWhhT; break;
        case 11: for (int i = base; i < 512; i += stride) ws[OFF_ENCB + i] = a.eBih[i] + a.eBhh[i]; return;
        case 12: for (int i = base; i < 512; i += stride) ws[OFF_MIDB + i] = a.mBih[i] + a.mBhh[i]; return;
        case 13: for (int i = base; i < 512; i += stride) ws[OFF_DECB + i] = a.dBih[i] + a.dBhh[i]; return;
        default: return;
    }
    int n = R * C;
    int rmask  = R - 1;
    int rshift = (R == 512) ? 9 : ((R == 128) ? 7 : 6);
    for (int o = base; o < n; o += stride) {
        int r = o & rmask, c = o >> rshift;
        ws[off + o] = src[r * C + c];
    }
}

// tile sequence: 35 tiles/step, staged round-robin into 2x40KB LDS
__device__ __forceinline__ void tile_src(int ti, int& off, int& is5) {
    if (ti < 4)       { off = OFF_WMT   + ti * 10240;     is5 = 1; }
    else if (ti == 4) { off = OFF_VdT;                    is5 = 0; }
    else if (ti < 9)  { off = OFF_eWihT + (ti - 5) * 8192;  is5 = 0; }
    else if (ti < 17) { off = OFF_eWhhT + (ti - 9) * 8192;  is5 = 0; }
    else if (ti < 25) { off = OFF_mWihT + (ti - 17) * 8192; is5 = 0; }
    else if (ti < 33) { off = OFF_mWhhT + (ti - 25) * 8192; is5 = 0; }
    else              { off = OFF_WxT   + (ti - 33) * 8192; is5 = 0; }
}

// issue staging loads for tile nti into registers (latency hidden by compute)
#define SLOT_PRE \
    int nti = ti + 1; if (nti == 35) nti = 0; \
    int soff, sn5; tile_src(nti, soff, sn5); \
    const float4* _sp = (const float4*)(ws + soff) + tid; \
    float4 _s0 = _sp[0], _s1 = _sp[512], _s2 = _sp[1024], _s3 = _sp[1536]; \
    float4 _s4 = make_float4(0.f, 0.f, 0.f, 0.f); \
    if (sn5) _s4 = _sp[2048];

// commit staged tile to the other buffer, barrier, flip
#define SLOT_POST \
    { float4* _dp = (float4*)sbuf[pp ^ 1] + tid; \
      _dp[0] = _s0; _dp[512] = _s1; _dp[1024] = _s2; _dp[1536] = _s3; \
      if (sn5) _dp[2048] = _s4; } \
    __syncthreads(); pp ^= 1; ti = nti;

// ---------------- persistent encoder + mid LSTM: 256 blocks x 512 thr, 4 rows/block ----------------
__global__ __launch_bounds__(512, 1) void enc_mid_kernel(
    const float* __restrict__ x_all,   // [B][Te][F]
    const float* __restrict__ Wi_b,
    const float* __restrict__ Vd_b,
    const float* __restrict__ Wx_b,
    float* __restrict__ ws)
{
    __shared__ __align__(16) float sbuf[2][10240];   // weight tile ping-pong (80KB)
    __shared__ __align__(16) float scratch[8192];    // avp/sp/gtp/wxp (time-disjoint union, 32KB)
    __shared__ __align__(16) float hcx[4][KM_];      // [h | c | x] per row
    __shared__ __align__(16) float hm[4][H_];
    __shared__ __align__(16) float cm[4][H_];
    __shared__ __align__(16) float xin[4][F_];
    __shared__ __align__(16) float xnext[4][F_];
    __shared__ __align__(16) float av[4][H_];
    __shared__ float bWi[H_], bVd[F_], bWx[H_], bE[G_], bM[G_];

    const int tid = threadIdx.x;
    const int b0  = blockIdx.x * 4;

    for (int i = tid; i < 4 * KM_; i += 512) hcx[i / KM_][i % KM_] = 0.f;
    ((float*)hm)[tid] = 0.f; ((float*)cm)[tid] = 0.f;
    if (tid < H_) { bWi[tid] = Wi_b[tid]; bWx[tid] = Wx_b[tid]; }
    if (tid < F_) bVd[tid] = Vd_b[tid];
    bE[tid] = ws[OFF_ENCB + tid];
    bM[tid] = ws[OFF_MIDB + tid];
    if (tid < 256) {  // x for t=0
        int r = tid >> 6, f = tid & 63;
        hcx[r][H2_ + f] = x_all[((b0 + r) * TE + 0) * F_ + f];
    }
    // prologue: stage tile 0 (WmT slice 0, 10240 floats) into sbuf[0]
    {
        const float4* sp0 = (const float4*)(ws + OFF_WMT) + tid;
        float4* dp0 = (float4*)sbuf[0] + tid;
        float4 a = sp0[0], b = sp0[512], c = sp0[1024], d = sp0[1536], e = sp0[2048];
        dp0[0] = a; dp0[512] = b; dp0[1024] = c; dp0[1536] = d; dp0[2048] = e;
    }
    __syncthreads();
    int ti = 0, pp = 0;

    for (int t = 0; t < TE; ++t) {
        // ---- A: m1 = [h|c|x] @ WmT  (tiles 0-3, kt=80; thread=(c128, ks4), k-range 20/tile)
        float mm0 = 0.f, mm1 = 0.f, mm2 = 0.f, mm3 = 0.f;
        for (int a = 0; a < 4; ++a) {
            SLOT_PRE
            {
                int c = tid & 127, ks = tid >> 7;
                const float* wb = sbuf[pp];
                int kb = ks * 20;
                #pragma unroll 4
                for (int kl = 0; kl < 20; ++kl) {
                    float w = wb[(kb + kl) * 128 + c];
                    int gk = a * 80 + kb + kl;
                    mm0 += w * hcx[0][gk]; mm1 += w * hcx[1][gk];
                    mm2 += w * hcx[2][gk]; mm3 += w * hcx[3][gk];
                }
                if (a == 3) {
                    scratch[ks * 512 +       c] = mm0;
                    scratch[ks * 512 + 128 + c] = mm1;
                    scratch[ks * 512 + 256 + c] = mm2;
                    scratch[ks * 512 + 384 + c] = mm3;
                }
            }
            SLOT_POST
        }
        // glue: combine + tanh -> av
        {
            int j = tid & 127, r = tid >> 7;
            float v = bWi[j] + (scratch[r * 128 + j]        + scratch[512 + r * 128 + j])
                             + (scratch[1024 + r * 128 + j] + scratch[1536 + r * 128 + j]);
            av[r][j] = tanh_fast(v);
        }
        __syncthreads();

        // ---- B: s-partials = av @ VdT  (tile 4; thread=(c64, ks8), k-range 16)
        {
            SLOT_PRE
            {
                int c = tid & 63, ks = tid >> 6;
                const float* wb = sbuf[pp];
                int kb = ks * 16;
                float a0 = 0.f, a1 = 0.f, a2 = 0.f, a3 = 0.f;
                #pragma unroll 4
                for (int kl = 0; kl < 16; ++kl) {
                    float w = wb[(kb + kl) * 64 + c];
                    int gk = kb + kl;
                    a0 += w * av[0][gk]; a1 += w * av[1][gk];
                    a2 += w * av[2][gk]; a3 += w * av[3][gk];
                }
                scratch[ks * 256 +       c] = a0;
                scratch[ks * 256 +  64 + c] = a1;
                scratch[ks * 256 + 128 + c] = a2;
                scratch[ks * 256 + 192 + c] = a3;
            }
            SLOT_POST
        }
        // glue: softmax over 64 -> xin (waves 0-3); waves 4-7 load x_{t+1}
        if (tid < 256) {
            int j = tid & 63, r = tid >> 6;
            float acc = bVd[j];
            #pragma unroll
            for (int ks = 0; ks < 8; ++ks) acc += scratch[ks * 256 + r * 64 + j];
            float m = acc;
            for (int off = 32; off > 0; off >>= 1) m = fmaxf(m, __shfl_xor(m, off, 64));
            float e = fexp2((acc - m) * LOG2E);
            float ssum = e;
            for (int off = 32; off > 0; off >>= 1) ssum += __shfl_xor(ssum, off, 64);
            xin[r][j] = hcx[r][H2_ + j] * e * frcp(ssum);
        } else if (t + 1 < TE) {
            int q = tid - 256, r = q >> 6, f = q & 63;
            xnext[r][f] = x_all[((b0 + r) * TE + (t + 1)) * F_ + f];
        }
        __syncthreads();

        // ---- C/D: enc gates = xin@eWih + h@eWhh  (tiles 5-16, kt=16; thread=(cf128, ks4))
        float4 g0 = make_float4(0.f, 0.f, 0.f, 0.f), g1 = g0, g2 = g0, g3 = g0;
        for (int g = 0; g < 12; ++g) {
            SLOT_PRE
            {
                int cf = tid & 127, ks = tid >> 7;
                const float4* wb4 = (const float4*)sbuf[pp];
                const float *A0, *A1, *A2, *A3; int kb;
                if (g < 4) { A0 = xin[0]; A1 = xin[1]; A2 = xin[2]; A3 = xin[3]; kb = g * 16; }
                else       { A0 = hcx[0]; A1 = hcx[1]; A2 = hcx[2]; A3 = hcx[3]; kb = (g - 4) * 16; }
                int k4 = ks * 4;
                #pragma unroll
                for (int kl = 0; kl < 4; ++kl) {
                    int lk = k4 + kl;
                    float4 w = wb4[lk * 128 + cf];
                    int gk = kb + lk;
                    float x0 = A0[gk], x1 = A1[gk], x2 = A2[gk], x3 = A3[gk];
                    FMA4(g0, w, x0); FMA4(g1, w, x1); FMA4(g2, w, x2); FMA4(g3, w, x3);
                }
                if (g == 11) {
                    ((float4*)(scratch + ks * 2048      ))[cf] = g0;
                    ((float4*)(scratch + ks * 2048 +  512))[cf] = g1;
                    ((float4*)(scratch + ks * 2048 + 1024))[cf] = g2;
                    ((float4*)(scratch + ks * 2048 + 1536))[cf] = g3;
                }
            }
            SLOT_POST
        }
        // glue: enc LSTM cell + install prefetched x
        {
            int j = tid & 127, r = tid >> 7;
            float gi = bE[j], gf = bE[j + 128], gg = bE[j + 256], go = bE[j + 384];
            #pragma unroll
            for (int ks = 0; ks < 4; ++ks) {
                const float* gp = scratch + ks * 2048 + r * 512;
                gi += gp[j]; gf += gp[j + 128]; gg += gp[j + 256]; go += gp[j + 384];
            }
            float c = sigm(gf) * hcx[r][H_ + j] + sigm(gi) * tanh_fast(gg);
            float h = sigm(go) * tanh_fast(c);
            hcx[r][H_ + j] = c; hcx[r][j] = h;
            if (tid < 256 && t + 1 < TE) {
                int rr = tid >> 6, f = tid & 63;
                hcx[rr][H2_ + f] = xnext[rr][f];
            }
        }
        __syncthreads();

        // ---- E/F: mid gates = h_enc@mWih + h_mid@mWhh  (tiles 17-32)
        g0 = make_float4(0.f, 0.f, 0.f, 0.f); g1 = g0; g2 = g0; g3 = g0;
        for (int g = 0; g < 16; ++g) {
            SLOT_PRE
            {
                int cf = tid & 127, ks = tid >> 7;
                const float4* wb4 = (const float4*)sbuf[pp];
                const float *A0, *A1, *A2, *A3; int kb;
                if (g < 8) { A0 = hcx[0]; A1 = hcx[1]; A2 = hcx[2]; A3 = hcx[3]; kb = g * 16; }
                else       { A0 = hm[0];  A1 = hm[1];  A2 = hm[2];  A3 = hm[3];  kb = (g - 8) * 16; }
                int k4 = ks * 4;
                #pragma unroll
                for (int kl = 0; kl < 4; ++kl) {
                    int lk = k4 + kl;
                    float4 w = wb4[lk * 128 + cf];
                    int gk = kb + lk;
                    float x0 = A0[gk], x1 = A1[gk], x2 = A2[gk], x3 = A3[gk];
                    FMA4(g0, w, x0); FMA4(g1, w, x1); FMA4(g2, w, x2); FMA4(g3, w, x3);
                }
                if (g == 15) {
                    ((float4*)(scratch + ks * 2048      ))[cf] = g0;
                    ((float4*)(scratch + ks * 2048 +  512))[cf] = g1;
                    ((float4*)(scratch + ks * 2048 + 1024))[cf] = g2;
                    ((float4*)(scratch + ks * 2048 + 1536))[cf] = g3;
                }
            }
            SLOT_POST
        }
        // glue: mid LSTM cell + store mid_out
        {
            int j = tid & 127, r = tid >> 7;
            float gi = bM[j], gf = bM[j + 128], gg = bM[j + 256], go = bM[j + 384];
            #pragma unroll
            for (int ks = 0; ks < 4; ++ks) {
                const float* gp = scratch + ks * 2048 + r * 512;
                gi += gp[j]; gf += gp[j + 128]; gg += gp[j + 256]; go += gp[j + 384];
            }
            float c = sigm(gf) * cm[r][j] + sigm(gi) * tanh_fast(gg);
            float h = sigm(go) * tanh_fast(c);
            cm[r][j] = c; hm[r][j] = h;
            ws[OFF_MID + ((size_t)(b0 + r) * TE + t) * H_ + j] = h;
        }
        __syncthreads();

        // ---- G: wx = h_mid @ WxT  (tiles 33-34, kt=64; thread=(c128, ks4), k-range 16)
        float wa0 = 0.f, wa1 = 0.f, wa2 = 0.f, wa3 = 0.f;
        for (int g = 0; g < 2; ++g) {
            SLOT_PRE
            {
                int c = tid & 127, ks = tid >> 7;
                const float* wb = sbuf[pp];
                int kb = ks * 16;
                #pragma unroll 4
                for (int kl = 0; kl < 16; ++kl) {
                    int lk = kb + kl;
                    float w = wb[lk * 128 + c];
                    int gk = g * 64 + lk;
                    wa0 += w * hm[0][gk]; wa1 += w * hm[1][gk];
                    wa2 += w * hm[2][gk]; wa3 += w * hm[3][gk];
                }
                if (g == 1) {
                    scratch[ks * 512 +       c] = wa0;
                    scratch[ks * 512 + 128 + c] = wa1;
                    scratch[ks * 512 + 256 + c] = wa2;
                    scratch[ks * 512 + 384 + c] = wa3;
                }
            }
            SLOT_POST
        }
        // glue: wx combine + store. No trailing barrier: next slot-0 only reads sbuf/hcx
        // (both stable) and first scratch write is 3 barriers away.
        {
            int j = tid & 127, r = tid >> 7;
            float v = bWx[j] + (scratch[r * 128 + j]        + scratch[512 + r * 128 + j])
                             + (scratch[1024 + r * 128 + j] + scratch[1536 + r * 128 + j]);
            ws[OFF_WX + ((size_t)(b0 + r) * TE + t) * H_ + j] = v;
        }
    }

    // final mid state -> decoder init (each thread wrote its own hm/cm element)
    {
        int j = tid & 127, r = tid >> 7;
        ws[OFF_STH + (b0 + r) * H_ + j] = hm[r][j];
        ws[OFF_STC + (b0 + r) * H_ + j] = cm[r][j];
    }
}

// ---------------- persistent decoder: 256 blocks x 512 thr, 4 rows/block (R2 + qv pad) ----------------
#define QP_ 132   // padded qv row stride kills the 4-way bank conflict in the score phase

__global__ __launch_bounds__(512, 1) void dec_kernel(
    const float* __restrict__ Vw_in,
    const float* __restrict__ Vb_in,
    const float* __restrict__ rw_in,
    const float* __restrict__ rb_in,
    const float* __restrict__ ws,
    float* __restrict__ out)
{
    __shared__ float hc2[4][H2_];      // [hi | ci]
    __shared__ float qv[4][QP_];       // q, then reused as dec_in
    __shared__ float sb[4][TE];
    __shared__ float dinp[4][4][H_];   // [ts][r][j]
    __shared__ float gt2[4][G_];
    __shared__ float bD[G_], Vw[H_], rw[H_];

    const int tid = threadIdx.x;
    const int b0  = blockIdx.x * 4;
    const float Vb = Vb_in[0], rb = rb_in[0];

    for (int i = tid; i < 4 * H2_; i += 512) {
        int r = i >> 8, c = i & 255;
        hc2[r][c] = (c < H_) ? ws[OFF_STH + (b0 + r) * H_ + c]
                             : ws[OFF_STC + (b0 + r) * H_ + (c - H_)];
    }
    if (tid < H_) { Vw[tid] = Vw_in[tid]; rw[tid] = rw_in[tid]; }
    bD[tid] = ws[OFF_DECB + tid];
    __syncthreads();

    const float*  WhT    = ws + OFF_WhT;                      // [256][128]
    const float4* dWihT4 = (const float4*)(ws + OFF_dWihT);   // [128][128] f4
    const float4* dWhhT4 = (const float4*)(ws + OFF_dWhhT);   // [128][128] f4
    const float4* wx4    = (const float4*)(ws + OFF_WX);
    const float4* mid4   = (const float4*)(ws + OFF_MID);

    for (int td = 0; td < TD; ++td) {
        // P1: q = [hi|ci]@WhT  [4][128]
        {
            int j = tid & 127, r = tid >> 7;
            float s0 = 0.f, s1 = 0.f, s2 = 0.f, s3 = 0.f;
            #pragma unroll 4
            for (int k = 0; k < H2_; k += 4) {
                s0 += WhT[(k    ) * H_ + j] * hc2[r][k    ];
                s1 += WhT[(k + 1) * H_ + j] * hc2[r][k + 1];
                s2 += WhT[(k + 2) * H_ + j] * hc2[r][k + 2];
                s3 += WhT[(k + 3) * H_ + j] * hc2[r][k + 3];
            }
            qv[r][j] = (s0 + s1) + (s2 + s3);
        }
        __syncthreads();

        // P2: scores sb[r][tp] = sum_h tanh(q[r][h] + wx[b][tp][h]) * Vw[h] + Vb
        for (int task = tid; task < 4 * TE; task += 512) {
            int r = task & 3, tp = task >> 2;
            const float4* wxr = wx4 + ((size_t)(b0 + r) * TE + tp) * (H_ / 4);
            float acc = Vb;
            #pragma unroll 8
            for (int kk = 0; kk < H_ / 4; ++kk) {
                float4 w = wxr[kk];
                int j = kk * 4;
                acc += tanh_fast(qv[r][j]     + w.x) * Vw[j];
                acc += tanh_fast(qv[r][j + 1] + w.y) * Vw[j + 1];
                acc += tanh_fast(qv[r][j + 2] + w.z) * Vw[j + 2];
                acc += tanh_fast(qv[r][j + 3] + w.w) * Vw[j + 3];
            }
            sb[r][tp] = acc;
        }
        __syncthreads();

        // P3: dec_in partials over tp chunks of 42
        {
            int ts = tid >> 7, r = (tid >> 5) & 3, cg = tid & 31;
            int t0 = ts * 42;
            float4 a = make_float4(0.f, 0.f, 0.f, 0.f);
            #pragma unroll 2
            for (int tp = t0; tp < t0 + 42; ++tp) {
                float s = sb[r][tp];
                float4 m = mid4[((size_t)(b0 + r) * TE + tp) * 32 + cg];
                a.x += s * m.x; a.y += s * m.y; a.z += s * m.z; a.w += s * m.w;
            }
            *(float4*)&dinp[ts][r][cg * 4] = a;
        }
        __syncthreads();
        // P3b: combine into qv (reused as dec_in)
        {
            int j = tid & 127, r = tid >> 7;
            qv[r][j] = (dinp[0][r][j] + dinp[1][r][j]) + (dinp[2][r][j] + dinp[3][r][j]);
        }
        __syncthreads();

        // P4: gates [4][512] = dec_in@dWihT + hi@dWhhT + bD
        {
            int cg = tid & 127, r = tid >> 7;
            int j0 = cg * 4;
            float4 b = *(const float4*)&bD[j0];
            float a0 = b.x, a1 = b.y, a2 = b.z, a3 = b.w;
            #pragma unroll 4
            for (int k = 0; k < H_; ++k) {
                float4 w = dWihT4[k * 128 + cg];
                float xv = qv[r][k];
                a0 += w.x * xv; a1 += w.y * xv; a2 += w.z * xv; a3 += w.w * xv;
            }
            #pragma unroll 4
            for (int k = 0; k < H_; ++k) {
                float4 w = dWhhT4[k * 128 + cg];
                float hv = hc2[r][k];
                a0 += w.x * hv; a1 += w.y * hv; a2 += w.z * hv; a3 += w.w * hv;
            }
            *(float4*)&gt2[r][j0] = make_float4(a0, a1, a2, a3);
        }
        __syncthreads();

        // P5: LSTM update
        {
            int j = tid & 127, r = tid >> 7;
            float gi = gt2[r][j], gf = gt2[r][j+128], gg = gt2[r][j+256], go = gt2[r][j+384];
            float c = sigm(gf) * hc2[r][H_ + j] + sigm(gi) * tanh_fast(gg);
            float h = sigm(go) * tanh_fast(c);
            hc2[r][H_ + j] = c; hc2[r][j] = h;
        }
        __syncthreads();

        // P6: out[b][td] = h . reg_w + reg_b  (one wave per row; no trailing barrier needed)
        if (tid < 256) {
            int r = tid >> 6, lane = tid & 63;
            float v = hc2[r][lane] * rw[lane] + hc2[r][lane + 64] * rw[lane + 64];
            for (int off = 32; off > 0; off >>= 1) v += __shfl_xor(v, off, 64);
            if (lane == 0) out[(b0 + r) * TD + td] = v + rb;
        }
    }
}

extern "C" void kernel_launch(void* const* d_in, const int* in_sizes, int n_in,
                              void* d_out, int out_size, void* d_ws, size_t ws_size,
                              hipStream_t stream)
{
    (void)in_sizes; (void)n_in; (void)out_size;
    if (ws_size < (size_t)WS_FLOATS * sizeof(float)) return;

    const float* x_all = (const float*)d_in[0];
    const float* Wi_b  = (const float*)d_in[3];
    const float* Vd_b  = (const float*)d_in[6];
    const float* Wx_b  = (const float*)d_in[16];
    const float* V_w   = (const float*)d_in[18];
    const float* V_b   = (const float*)d_in[19];
    const float* reg_w = (const float*)d_in[24];
    const float* reg_b = (const float*)d_in[25];
    float* ws  = (float*)d_ws;
    float* out = (float*)d_out;

    PrepArgs pa{
        (const float*)d_in[4],  // We_w
        (const float*)d_in[2],  // Wi_w
        (const float*)d_in[5],  // Vd_w
        (const float*)d_in[7],  // enc_Wih
        (const float*)d_in[8],  // enc_Whh
        (const float*)d_in[9],  // enc_bih
        (const float*)d_in[10], // enc_bhh
        (const float*)d_in[11], // mid_Wih
        (const float*)d_in[12], // mid_Whh
        (const float*)d_in[13], // mid_bih
        (const float*)d_in[14], // mid_bhh
        (const float*)d_in[15], // Wx_w
        (const float*)d_in[17], // Wh_w
        (const float*)d_in[20], // dec_Wih
        (const float*)d_in[21], // dec_Whh
        (const float*)d_in[22], // dec_bih
        (const float*)d_in[23]  // dec_bhh
    };

    prep_kernel<<<56, 256, 0, stream>>>(pa, ws);
    enc_mid_kernel<<<256, 512, 0, stream>>>(x_all, Wi_b, Vd_b, Wx_b, ws);
    dec_kernel<<<256, 512, 0, stream>>>(V_w, V_b, reg_w, reg_b, ws, out);
}

// Round 6
// 4919.803 us; speedup vs baseline: 3.1233x; 2.0476x over previous
//
#include <hip/hip_runtime.h>

#define B_   1024
#define TE   168
#define TD   24
#define F_   64
#define H_   128
#define H2_  256
#define G_   512
#define KM_  320   // combined [h|c|x] K for m1

// ---- workspace float offsets ----
#define OFF_WMT    0          // [320][128]  rows 0..255 = We^T, 256..319 = Wi^T
#define OFF_VdT    40960      // [128][64]
#define OFF_eWihT  49152      // [64][512]
#define OFF_eWhhT  81920      // [128][512]
#define OFF_mWihT  147456     // [128][512]
#define OFF_mWhhT  212992     // [128][512]
#define OFF_WxT    278528     // [128][128]
#define OFF_WhT    294912     // [256][128]
#define OFF_dWihT  327680     // [128][512]
#define OFF_dWhhT  393216     // [128][512]
#define OFF_ENCB   458752     // [512] bih+bhh
#define OFF_MIDB   459264
#define OFF_DECB   459776
#define OFF_MID    460800                      // [1024][168][128]
#define OFF_WX     (OFF_MID + B_*TE*H_)        // [1024][168][128]
#define OFF_STH    (OFF_WX  + B_*TE*H_)        // [1024][128]
#define OFF_STC    (OFF_STH + B_*H_)
#define WS_FLOATS  (OFF_STC + B_*H_)

__device__ __forceinline__ float fexp2(float x) { return __builtin_amdgcn_exp2f(x); }
__device__ __forceinline__ float frcp(float x)  { return __builtin_amdgcn_rcpf(x); }
#define LOG2E 1.4426950408889634f

__device__ __forceinline__ float sigm(float x) {
    return frcp(1.f + fexp2(-LOG2E * x));
}
__device__ __forceinline__ float tanh_fast(float x) {
    float e = fexp2(2.f * LOG2E * x);
    return 1.f - 2.f * frcp(e + 1.f);
}

#define FMA4(g, w, s) { g.x += w.x*(s); g.y += w.y*(s); g.z += w.z*(s); g.w += w.w*(s); }

// ---------------- prep: transpose weights to [K][N], sum bias pairs ----------------
struct PrepArgs {
    const float *We, *Wi, *Vd, *eWih, *eWhh, *eBih, *eBhh,
                *mWih, *mWhh, *mBih, *mBhh, *Wx, *Wh, *dWih, *dWhh, *dBih, *dBhh;
};

__global__ void prep_kernel(PrepArgs a, float* __restrict__ ws) {
    int sec  = blockIdx.x >> 2;
    int base = (blockIdx.x & 3) * blockDim.x + threadIdx.x;
    const int stride = blockDim.x * 4;
    const float* src = nullptr; int R = 0, C = 0, off = 0;
    switch (sec) {
        case 0:  src = a.We;   R = 128; C = 256; off = OFF_WMT;           break;
        case 1:  src = a.Wi;   R = 128; C = 64;  off = OFF_WMT + 32768;   break;
        case 2:  src = a.Vd;   R = 64;  C = 128; off = OFF_VdT;   break;
        case 3:  src = a.eWih; R = 512; C = 64;  off = OFF_eWihT; break;
        case 4:  src = a.eWhh; R = 512; C = 128; off = OFF_eWhhT; break;
        case 5:  src = a.mWih; R = 512; C = 128; off = OFF_mWihT; break;
        case 6:  src = a.mWhh; R = 512; C = 128; off = OFF_mWhhT; break;
        case 7:  src = a.Wx;   R = 128; C = 128; off = OFF_WxT;   break;
        case 8:  src = a.Wh;   R = 128; C = 256; off = OFF_WhT;   break;
        case 9:  src = a.dWih; R = 512; C = 128; off = OFF_dWihT; break;
        case 10: src = a.dWhh; R = 512; C = 128; off = OFF_dWhhT; break;
        case 11: for (int i = base; i < 512; i += stride) ws[OFF_ENCB + i] = a.eBih[i] + a.eBhh[i]; return;
        case 12: for (int i = base; i < 512; i += stride) ws[OFF_MIDB + i] = a.mBih[i] + a.mBhh[i]; return;
        case 13: for (int i = base; i < 512; i += stride) ws[OFF_DECB + i] = a.dBih[i] + a.dBhh[i]; return;
        default: return;
    }
    int n = R * C;
    int rmask  = R - 1;
    int rshift = (R == 512) ? 9 : ((R == 128) ? 7 : 6);
    for (int o = base; o < n; o += stride) {
        int r = o & rmask, c = o >> rshift;
        ws[off + o] = src[r * C + c];
    }
}

// ---------------- persistent encoder + mid LSTM: 256 blocks x 512 thr, 4 rows/block ----------------
// Each weight element is loaded from L2 exactly ONCE per block per step; every thread
// accumulates partials for all 4 batch rows (k-split across thread groups, LDS combine).
__global__ __launch_bounds__(512, 1) void enc_mid_kernel(
    const float* __restrict__ x_all,   // [B][Te][F]
    const float* __restrict__ Wi_b,
    const float* __restrict__ Vd_b,
    const float* __restrict__ Wx_b,
    float* __restrict__ ws)
{
    __shared__ __align__(16) float scratch[8192];    // k-split partials (time-disjoint reuse, 32KB)
    __shared__ __align__(16) float hcx[4][KM_];      // [h | c | x] per row
    __shared__ __align__(16) float hm[4][H_];
    __shared__ __align__(16) float cm[4][H_];
    __shared__ __align__(16) float xin[4][F_];
    __shared__ __align__(16) float xnext[4][F_];
    __shared__ __align__(16) float av[4][H_];
    __shared__ float bWi[H_], bVd[F_], bWx[H_], bE[G_], bM[G_];

    const int tid = threadIdx.x;
    const int b0  = blockIdx.x * 4;

    for (int i = tid; i < 4 * KM_; i += 512) hcx[i / KM_][i % KM_] = 0.f;
    ((float*)hm)[tid] = 0.f; ((float*)cm)[tid] = 0.f;
    if (tid < H_) { bWi[tid] = Wi_b[tid]; bWx[tid] = Wx_b[tid]; }
    if (tid < F_) bVd[tid] = Vd_b[tid];
    bE[tid] = ws[OFF_ENCB + tid];
    bM[tid] = ws[OFF_MIDB + tid];
    if (tid < 256) {  // x for t=0
        int r = tid >> 6, f = tid & 63;
        hcx[r][H2_ + f] = x_all[((b0 + r) * TE + 0) * F_ + f];
    }
    __syncthreads();

    const float4* WmT4   = (const float4*)(ws + OFF_WMT);     // [320][32] f4
    const float4* VdT4   = (const float4*)(ws + OFF_VdT);     // [128][16] f4
    const float4* eWihT4 = (const float4*)(ws + OFF_eWihT);   // [64][128] f4
    const float4* eWhhT4 = (const float4*)(ws + OFF_eWhhT);   // [128][128] f4
    const float4* mWihT4 = (const float4*)(ws + OFF_mWihT);   // [128][128] f4
    const float4* mWhhT4 = (const float4*)(ws + OFF_mWhhT);   // [128][128] f4
    const float4* WxT4   = (const float4*)(ws + OFF_WxT);     // [128][32] f4

    for (int t = 0; t < TE; ++t) {
        // ---- P1: m1 partials = [h|c|x] @ WmT   (thread = (cg32, ks16), 20 k each)
        {
            int cg = tid & 31, ks = tid >> 5;
            int k0 = ks * 20;
            float4 a0 = make_float4(0.f,0.f,0.f,0.f), a1 = a0, a2 = a0, a3 = a0;
            #pragma unroll 5
            for (int k = k0; k < k0 + 20; ++k) {
                float4 w = WmT4[k * 32 + cg];
                FMA4(a0, w, hcx[0][k]); FMA4(a1, w, hcx[1][k]);
                FMA4(a2, w, hcx[2][k]); FMA4(a3, w, hcx[3][k]);
            }
            float* sp = scratch + ks * 512 + cg * 4;
            *(float4*)(sp      ) = a0;
            *(float4*)(sp + 128) = a1;
            *(float4*)(sp + 256) = a2;
            *(float4*)(sp + 384) = a3;
        }
        __syncthreads();
        // P1c: combine 16 partials + bias + tanh -> av
        {
            int j = tid & 127, r = tid >> 7;
            const float* sp = scratch + r * 128 + j;
            float v = bWi[j];
            #pragma unroll
            for (int ks = 0; ks < 16; ++ks) v += sp[ks * 512];
            av[r][j] = tanh_fast(v);
        }
        __syncthreads();

        // ---- P3a: s partials = av @ VdT   (thread = (cg16, ks32), 4 k each)
        {
            int cg = tid & 15, ks = tid >> 4;
            int k0 = ks * 4;
            float4 a0 = make_float4(0.f,0.f,0.f,0.f), a1 = a0, a2 = a0, a3 = a0;
            #pragma unroll
            for (int k = k0; k < k0 + 4; ++k) {
                float4 w = VdT4[k * 16 + cg];
                FMA4(a0, w, av[0][k]); FMA4(a1, w, av[1][k]);
                FMA4(a2, w, av[2][k]); FMA4(a3, w, av[3][k]);
            }
            float* sp = scratch + ks * 256 + cg * 4;
            *(float4*)(sp      ) = a0;
            *(float4*)(sp +  64) = a1;
            *(float4*)(sp + 128) = a2;
            *(float4*)(sp + 192) = a3;
        }
        __syncthreads();
        // P3b: combine 32 + softmax over 64 -> xin (waves 0-3); waves 4-7 prefetch x_{t+1}
        if (tid < 256) {
            int j = tid & 63, r = tid >> 6;
            const float* sp = scratch + r * 64 + j;
            float acc = bVd[j];
            #pragma unroll
            for (int ks = 0; ks < 32; ++ks) acc += sp[ks * 256];
            float m = acc;
            for (int off = 32; off > 0; off >>= 1) m = fmaxf(m, __shfl_xor(m, off, 64));
            float e = fexp2((acc - m) * LOG2E);
            float ssum = e;
            for (int off = 32; off > 0; off >>= 1) ssum += __shfl_xor(ssum, off, 64);
            xin[r][j] = hcx[r][H2_ + j] * e * frcp(ssum);
        } else if (t + 1 < TE) {
            int q = tid - 256, r = q >> 6, f = q & 63;
            xnext[r][f] = x_all[((b0 + r) * TE + (t + 1)) * F_ + f];
        }
        __syncthreads();

        // ---- P4: enc gate partials = xin@eWih (K=64) + h@eWhh (K=128)  (thread = (cg128, ks4))
        {
            int cg = tid & 127, ks = tid >> 7;
            float4 g0 = make_float4(0.f,0.f,0.f,0.f), g1 = g0, g2 = g0, g3 = g0;
            int ka = ks * 16;
            #pragma unroll 8
            for (int k = ka; k < ka + 16; ++k) {
                float4 w = eWihT4[k * 128 + cg];
                FMA4(g0, w, xin[0][k]); FMA4(g1, w, xin[1][k]);
                FMA4(g2, w, xin[2][k]); FMA4(g3, w, xin[3][k]);
            }
            int kb = ks * 32;
            #pragma unroll 8
            for (int k = kb; k < kb + 32; ++k) {
                float4 w = eWhhT4[k * 128 + cg];
                FMA4(g0, w, hcx[0][k]); FMA4(g1, w, hcx[1][k]);
                FMA4(g2, w, hcx[2][k]); FMA4(g3, w, hcx[3][k]);
            }
            float* sp = scratch + ks * 2048 + cg * 4;
            *(float4*)(sp       ) = g0;
            *(float4*)(sp +  512) = g1;
            *(float4*)(sp + 1024) = g2;
            *(float4*)(sp + 1536) = g3;
        }
        __syncthreads();
        // P4c: combine 4 partials/gate + enc LSTM cell; threads 0-255 install prefetched x
        {
            int j = tid & 127, r = tid >> 7;
            const float* sp = scratch + r * 512;
            float gi = bE[j], gf = bE[j + 128], gg = bE[j + 256], go = bE[j + 384];
            #pragma unroll
            for (int ks = 0; ks < 4; ++ks) {
                const float* p = sp + ks * 2048;
                gi += p[j]; gf += p[j + 128]; gg += p[j + 256]; go += p[j + 384];
            }
            float c = sigm(gf) * hcx[r][H_ + j] + sigm(gi) * tanh_fast(gg);
            float h = sigm(go) * tanh_fast(c);
            hcx[r][H_ + j] = c; hcx[r][j] = h;
            if (tid < 256 && t + 1 < TE) {
                int rr = tid >> 6, f = tid & 63;
                hcx[rr][H2_ + f] = xnext[rr][f];
            }
        }
        __syncthreads();

        // ---- P6: mid gate partials = h_enc@mWih (K=128) + h_mid@mWhh (K=128)
        {
            int cg = tid & 127, ks = tid >> 7;
            float4 g0 = make_float4(0.f,0.f,0.f,0.f), g1 = g0, g2 = g0, g3 = g0;
            int kb = ks * 32;
            #pragma unroll 8
            for (int k = kb; k < kb + 32; ++k) {
                float4 w = mWihT4[k * 128 + cg];
                FMA4(g0, w, hcx[0][k]); FMA4(g1, w, hcx[1][k]);
                FMA4(g2, w, hcx[2][k]); FMA4(g3, w, hcx[3][k]);
            }
            #pragma unroll 8
            for (int k = kb; k < kb + 32; ++k) {
                float4 w = mWhhT4[k * 128 + cg];
                FMA4(g0, w, hm[0][k]); FMA4(g1, w, hm[1][k]);
                FMA4(g2, w, hm[2][k]); FMA4(g3, w, hm[3][k]);
            }
            float* sp = scratch + ks * 2048 + cg * 4;
            *(float4*)(sp       ) = g0;
            *(float4*)(sp +  512) = g1;
            *(float4*)(sp + 1024) = g2;
            *(float4*)(sp + 1536) = g3;
        }
        __syncthreads();
        // P6c: combine + mid LSTM cell + store mid_out
        {
            int j = tid & 127, r = tid >> 7;
            const float* sp = scratch + r * 512;
            float gi = bM[j], gf = bM[j + 128], gg = bM[j + 256], go = bM[j + 384];
            #pragma unroll
            for (int ks = 0; ks < 4; ++ks) {
                const float* p = sp + ks * 2048;
                gi += p[j]; gf += p[j + 128]; gg += p[j + 256]; go += p[j + 384];
            }
            float c = sigm(gf) * cm[r][j] + sigm(gi) * tanh_fast(gg);
            float h = sigm(go) * tanh_fast(c);
            cm[r][j] = c; hm[r][j] = h;
            ws[OFF_MID + ((size_t)(b0 + r) * TE + t) * H_ + j] = h;
        }
        __syncthreads();

        // ---- P8: wx partials = h_mid @ WxT   (thread = (cg32, ks16), 8 k each)
        {
            int cg = tid & 31, ks = tid >> 5;
            int k0 = ks * 8;
            float4 a0 = make_float4(0.f,0.f,0.f,0.f), a1 = a0, a2 = a0, a3 = a0;
            #pragma unroll
            for (int k = k0; k < k0 + 8; ++k) {
                float4 w = WxT4[k * 32 + cg];
                FMA4(a0, w, hm[0][k]); FMA4(a1, w, hm[1][k]);
                FMA4(a2, w, hm[2][k]); FMA4(a3, w, hm[3][k]);
            }
            float* sp = scratch + ks * 512 + cg * 4;
            *(float4*)(sp      ) = a0;
            *(float4*)(sp + 128) = a1;
            *(float4*)(sp + 256) = a2;
            *(float4*)(sp + 384) = a3;
        }
        __syncthreads();
        // P8c: combine + store wx
        {
            int j = tid & 127, r = tid >> 7;
            const float* sp = scratch + r * 128 + j;
            float v = bWx[j];
            #pragma unroll
            for (int ks = 0; ks < 16; ++ks) v += sp[ks * 512];
            ws[OFF_WX + ((size_t)(b0 + r) * TE + t) * H_ + j] = v;
        }
        __syncthreads();   // scratch reused by next-step P1
    }

    {
        int j = tid & 127, r = tid >> 7;
        ws[OFF_STH + (b0 + r) * H_ + j] = hm[r][j];
        ws[OFF_STC + (b0 + r) * H_ + j] = cm[r][j];
    }
}

// ---------------- persistent decoder: 256 blocks x 512 thr, 4 rows/block (R2 + qv pad) ----------------
#define QP_ 132   // padded qv row stride kills the 4-way bank conflict in the score phase

__global__ __launch_bounds__(512, 1) void dec_kernel(
    const float* __restrict__ Vw_in,
    const float* __restrict__ Vb_in,
    const float* __restrict__ rw_in,
    const float* __restrict__ rb_in,
    const float* __restrict__ ws,
    float* __restrict__ out)
{
    __shared__ float hc2[4][H2_];      // [hi | ci]
    __shared__ float qv[4][QP_];       // q, then reused as dec_in
    __shared__ float sb[4][TE];
    __shared__ float dinp[4][4][H_];   // [ts][r][j]
    __shared__ float gt2[4][G_];
    __shared__ float bD[G_], Vw[H_], rw[H_];

    const int tid = threadIdx.x;
    const int b0  = blockIdx.x * 4;
    const float Vb = Vb_in[0], rb = rb_in[0];

    for (int i = tid; i < 4 * H2_; i += 512) {
        int r = i >> 8, c = i & 255;
        hc2[r][c] = (c < H_) ? ws[OFF_STH + (b0 + r) * H_ + c]
                             : ws[OFF_STC + (b0 + r) * H_ + (c - H_)];
    }
    if (tid < H_) { Vw[tid] = Vw_in[tid]; rw[tid] = rw_in[tid]; }
    bD[tid] = ws[OFF_DECB + tid];
    __syncthreads();

    const float*  WhT    = ws + OFF_WhT;                      // [256][128]
    const float4* dWihT4 = (const float4*)(ws + OFF_dWihT);   // [128][128] f4
    const float4* dWhhT4 = (const float4*)(ws + OFF_dWhhT);   // [128][128] f4
    const float4* wx4    = (const float4*)(ws + OFF_WX);
    const float4* mid4   = (const float4*)(ws + OFF_MID);

    for (int td = 0; td < TD; ++td) {
        // P1: q = [hi|ci]@WhT  [4][128]
        {
            int j = tid & 127, r = tid >> 7;
            float s0 = 0.f, s1 = 0.f, s2 = 0.f, s3 = 0.f;
            #pragma unroll 4
            for (int k = 0; k < H2_; k += 4) {
                s0 += WhT[(k    ) * H_ + j] * hc2[r][k    ];
                s1 += WhT[(k + 1) * H_ + j] * hc2[r][k + 1];
                s2 += WhT[(k + 2) * H_ + j] * hc2[r][k + 2];
                s3 += WhT[(k + 3) * H_ + j] * hc2[r][k + 3];
            }
            qv[r][j] = (s0 + s1) + (s2 + s3);
        }
        __syncthreads();

        // P2: scores sb[r][tp] = sum_h tanh(q[r][h] + wx[b][tp][h]) * Vw[h] + Vb
        for (int task = tid; task < 4 * TE; task += 512) {
            int r = task & 3, tp = task >> 2;
            const float4* wxr = wx4 + ((size_t)(b0 + r) * TE + tp) * (H_ / 4);
            float acc = Vb;
            #pragma unroll 8
            for (int kk = 0; kk < H_ / 4; ++kk) {
                float4 w = wxr[kk];
                int j = kk * 4;
                acc += tanh_fast(qv[r][j]     + w.x) * Vw[j];
                acc += tanh_fast(qv[r][j + 1] + w.y) * Vw[j + 1];
                acc += tanh_fast(qv[r][j + 2] + w.z) * Vw[j + 2];
                acc += tanh_fast(qv[r][j + 3] + w.w) * Vw[j + 3];
            }
            sb[r][tp] = acc;
        }
        __syncthreads();

        // P3: dec_in partials over tp chunks of 42
        {
            int ts = tid >> 7, r = (tid >> 5) & 3, cg = tid & 31;
            int t0 = ts * 42;
            float4 a = make_float4(0.f, 0.f, 0.f, 0.f);
            #pragma unroll 2
            for (int tp = t0; tp < t0 + 42; ++tp) {
                float s = sb[r][tp];
                float4 m = mid4[((size_t)(b0 + r) * TE + tp) * 32 + cg];
                a.x += s * m.x; a.y += s * m.y; a.z += s * m.z; a.w += s * m.w;
            }
            *(float4*)&dinp[ts][r][cg * 4] = a;
        }
        __syncthreads();
        // P3b: combine into qv (reused as dec_in)
        {
            int j = tid & 127, r = tid >> 7;
            qv[r][j] = (dinp[0][r][j] + dinp[1][r][j]) + (dinp[2][r][j] + dinp[3][r][j]);
        }
        __syncthreads();

        // P4: gates [4][512] = dec_in@dWihT + hi@dWhhT + bD
        {
            int cg = tid & 127, r = tid >> 7;
            int j0 = cg * 4;
            float4 b = *(const float4*)&bD[j0];
            float a0 = b.x, a1 = b.y, a2 = b.z, a3 = b.w;
            #pragma unroll 4
            for (int k = 0; k < H_; ++k) {
                float4 w = dWihT4[k * 128 + cg];
                float xv = qv[r][k];
                a0 += w.x * xv; a1 += w.y * xv; a2 += w.z * xv; a3 += w.w * xv;
            }
            #pragma unroll 4
            for (int k = 0; k < H_; ++k) {
                float4 w = dWhhT4[k * 128 + cg];
                float hv = hc2[r][k];
                a0 += w.x * hv; a1 += w.y * hv; a2 += w.z * hv; a3 += w.w * hv;
            }
            *(float4*)&gt2[r][j0] = make_float4(a0, a1, a2, a3);
        }
        __syncthreads();

        // P5: LSTM update
        {
            int j = tid & 127, r = tid >> 7;
            float gi = gt2[r][j], gf = gt2[r][j+128], gg = gt2[r][j+256], go = gt2[r][j+384];
            float c = sigm(gf) * hc2[r][H_ + j] + sigm(gi) * tanh_fast(gg);
            float h = sigm(go) * tanh_fast(c);
            hc2[r][H_ + j] = c; hc2[r][j] = h;
        }
        __syncthreads();

        // P6: out[b][td] = h . reg_w + reg_b  (one wave per row; no trailing barrier needed)
        if (tid < 256) {
            int r = tid >> 6, lane = tid & 63;
            float v = hc2[r][lane] * rw[lane] + hc2[r][lane + 64] * rw[lane + 64];
            for (int off = 32; off > 0; off >>= 1) v += __shfl_xor(v, off, 64);
            if (lane == 0) out[(b0 + r) * TD + td] = v + rb;
        }
    }
}

extern "C" void kernel_launch(void* const* d_in, const int* in_sizes, int n_in,
                              void* d_out, int out_size, void* d_ws, size_t ws_size,
                              hipStream_t stream)
{
    (void)in_sizes; (void)n_in; (void)out_size;
    if (ws_size < (size_t)WS_FLOATS * sizeof(float)) return;

    const float* x_all = (const float*)d_in[0];
    const float* Wi_b  = (const float*)d_in[3];
    const float* Vd_b  = (const float*)d_in[6];
    const float* Wx_b  = (const float*)d_in[16];
    const float* V_w   = (const float*)d_in[18];
    const float* V_b   = (const float*)d_in[19];
    const float* reg_w = (const float*)d_in[24];
    const float* reg_b = (const float*)d_in[25];
    float* ws  = (float*)d_ws;
    float* out = (float*)d_out;

    PrepArgs pa{
        (const float*)d_in[4],  // We_w
        (const float*)d_in[2],  // Wi_w
        (const float*)d_in[5],  // Vd_w
        (const float*)d_in[7],  // enc_Wih
        (const float*)d_in[8],  // enc_Whh
        (const float*)d_in[9],  // enc_bih
        (const float*)d_in[10], // enc_bhh
        (const float*)d_in[11], // mid_Wih
        (const float*)d_in[12], // mid_Whh
        (const float*)d_in[13], // mid_bih
        (const float*)d_in[14], // mid_bhh
        (const float*)d_in[15], // Wx_w
        (const float*)d_in[17], // Wh_w
        (const float*)d_in[20], // dec_Wih
        (const float*)d_in[21], // dec_Whh
        (const float*)d_in[22], // dec_bih
        (const float*)d_in[23]  // dec_bhh
    };

    prep_kernel<<<56, 256, 0, stream>>>(pa, ws);
    enc_mid_kernel<<<256, 512, 0, stream>>>(x_all, Wi_b, Vd_b, Wx_b, ws);
    dec_kernel<<<256, 512, 0, stream>>>(V_w, V_b, reg_w, reg_b, ws, out);
}

// Round 8
// 2997.710 us; speedup vs baseline: 5.1260x; 1.6412x over previous
//
#include <hip/hip_runtime.h>

#define B_   1024
#define TE   168
#define TD   24
#define F_   64
#define H_   128
#define H2_  256
#define G_   512
#define KM_  320   // combined [h|c|x] K for m1

// ---- workspace float offsets ----
#define OFF_WMT    0          // [320][128]  rows 0..255 = We^T, 256..319 = Wi^T
#define OFF_VdT    40960      // [128][64]
#define OFF_eWihT  49152      // [64][512]
#define OFF_eWhhT  81920      // [128][512]
#define OFF_mWihT  147456     // [128][512]
#define OFF_mWhhT  212992     // [128][512]
#define OFF_WxT    278528     // [128][128]
#define OFF_WhT    294912     // [256][128]
#define OFF_dWihT  327680     // [128][512]
#define OFF_dWhhT  393216     // [128][512]
#define OFF_ENCB   458752     // [512] bih+bhh
#define OFF_MIDB   459264
#define OFF_DECB   459776
#define OFF_MID    460800                      // [1024][168][128]
#define OFF_WX     (OFF_MID + B_*TE*H_)        // [1024][168][128]
#define OFF_STH    (OFF_WX  + B_*TE*H_)        // [1024][128]
#define OFF_STC    (OFF_STH + B_*H_)
#define WS_FLOATS  (OFF_STC + B_*H_)

__device__ __forceinline__ float fexp2(float x) { return __builtin_amdgcn_exp2f(x); }
__device__ __forceinline__ float frcp(float x)  { return __builtin_amdgcn_rcpf(x); }
#define LOG2E 1.4426950408889634f

__device__ __forceinline__ float sigm(float x) {
    return frcp(1.f + fexp2(-LOG2E * x));
}
__device__ __forceinline__ float tanh_fast(float x) {
    float e = fexp2(2.f * LOG2E * x);
    return 1.f - 2.f * frcp(e + 1.f);
}

// safe (function, not macro): acc += wv * s elementwise
__device__ __forceinline__ void fma4(float4& g, const float4 wv, const float s) {
    g.x = __builtin_fmaf(wv.x, s, g.x);
    g.y = __builtin_fmaf(wv.y, s, g.y);
    g.z = __builtin_fmaf(wv.z, s, g.z);
    g.w = __builtin_fmaf(wv.w, s, g.w);
}

// 4-k group: 4 weight float4 loads + 4 activation b128 reads -> 16 fma4
// accumulates into a0..a3 (must be in scope). Macro params chosen to avoid
// collision with struct member tokens (.x/.y/.z/.w).
#define GRP4(WT, STRIDE, CGV, KK, A0, A1, A2, A3)                         \
    {                                                                     \
        float4 wv0 = WT[(KK + 0) * STRIDE + CGV];                         \
        float4 wv1 = WT[(KK + 1) * STRIDE + CGV];                         \
        float4 wv2 = WT[(KK + 2) * STRIDE + CGV];                         \
        float4 wv3 = WT[(KK + 3) * STRIDE + CGV];                         \
        float4 xv0 = *(const float4*)&A0[KK];                             \
        float4 xv1 = *(const float4*)&A1[KK];                             \
        float4 xv2 = *(const float4*)&A2[KK];                             \
        float4 xv3 = *(const float4*)&A3[KK];                             \
        fma4(a0, wv0, xv0.x); fma4(a0, wv1, xv0.y); fma4(a0, wv2, xv0.z); fma4(a0, wv3, xv0.w); \
        fma4(a1, wv0, xv1.x); fma4(a1, wv1, xv1.y); fma4(a1, wv2, xv1.z); fma4(a1, wv3, xv1.w); \
        fma4(a2, wv0, xv2.x); fma4(a2, wv1, xv2.y); fma4(a2, wv2, xv2.z); fma4(a2, wv3, xv2.w); \
        fma4(a3, wv0, xv3.x); fma4(a3, wv1, xv3.y); fma4(a3, wv2, xv3.z); fma4(a3, wv3, xv3.w); \
    }

// ---------------- prep: transpose weights to [K][N], sum bias pairs ----------------
struct PrepArgs {
    const float *We, *Wi, *Vd, *eWih, *eWhh, *eBih, *eBhh,
                *mWih, *mWhh, *mBih, *mBhh, *Wx, *Wh, *dWih, *dWhh, *dBih, *dBhh;
};

__global__ void prep_kernel(PrepArgs a, float* __restrict__ ws) {
    int sec  = blockIdx.x >> 2;
    int base = (blockIdx.x & 3) * blockDim.x + threadIdx.x;
    const int stride = blockDim.x * 4;
    const float* src = nullptr; int R = 0, C = 0, off = 0;
    switch (sec) {
        case 0:  src = a.We;   R = 128; C = 256; off = OFF_WMT;           break;
        case 1:  src = a.Wi;   R = 128; C = 64;  off = OFF_WMT + 32768;   break;
        case 2:  src = a.Vd;   R = 64;  C = 128; off = OFF_VdT;   break;
        case 3:  src = a.eWih; R = 512; C = 64;  off = OFF_eWihT; break;
        case 4:  src = a.eWhh; R = 512; C = 128; off = OFF_eWhhT; break;
        case 5:  src = a.mWih; R = 512; C = 128; off = OFF_mWihT; break;
        case 6:  src = a.mWhh; R = 512; C = 128; off = OFF_mWhhT; break;
        case 7:  src = a.Wx;   R = 128; C = 128; off = OFF_WxT;   break;
        case 8:  src = a.Wh;   R = 128; C = 256; off = OFF_WhT;   break;
        case 9:  src = a.dWih; R = 512; C = 128; off = OFF_dWihT; break;
        case 10: src = a.dWhh; R = 512; C = 128; off = OFF_dWhhT; break;
        case 11: for (int i = base; i < 512; i += stride) ws[OFF_ENCB + i] = a.eBih[i] + a.eBhh[i]; return;
        case 12: for (int i = base; i < 512; i += stride) ws[OFF_MIDB + i] = a.mBih[i] + a.mBhh[i]; return;
        case 13: for (int i = base; i < 512; i += stride) ws[OFF_DECB + i] = a.dBih[i] + a.dBhh[i]; return;
        default: return;
    }
    int n = R * C;
    int rmask  = R - 1;
    int rshift = (R == 512) ? 9 : ((R == 128) ? 7 : 6);
    for (int o = base; o < n; o += stride) {
        int r = o & rmask, c = o >> rshift;
        ws[off + o] = src[r * C + c];
    }
}

// ---------------- persistent encoder + mid LSTM: 256 blocks x 512 thr, 4 rows/block ----------------
// Weights read from L2 exactly once per block per step; each thread accumulates all 4 rows.
__global__ __launch_bounds__(512, 1) void enc_mid_kernel(
    const float* __restrict__ x_all,   // [B][Te][F]
    const float* __restrict__ Wi_b,
    const float* __restrict__ Vd_b,
    const float* __restrict__ Wx_b,
    float* __restrict__ ws)
{
    __shared__ __align__(16) float scratch[8192];    // k-split partials (time-disjoint reuse, 32KB)
    __shared__ __align__(16) float hcx[4][KM_];      // [h | c | x] per row
    __shared__ __align__(16) float hm[4][H_];
    __shared__ __align__(16) float cm[4][H_];
    __shared__ __align__(16) float xin[4][F_];
    __shared__ __align__(16) float xnext[4][F_];
    __shared__ __align__(16) float av[4][H_];
    __shared__ float bWi[H_], bVd[F_], bWx[H_], bE[G_], bM[G_];

    const int tid = threadIdx.x;
    const int b0  = blockIdx.x * 4;

    for (int i = tid; i < 4 * KM_; i += 512) hcx[i / KM_][i % KM_] = 0.f;
    ((float*)hm)[tid] = 0.f; ((float*)cm)[tid] = 0.f;
    if (tid < H_) { bWi[tid] = Wi_b[tid]; bWx[tid] = Wx_b[tid]; }
    if (tid < F_) bVd[tid] = Vd_b[tid];
    bE[tid] = ws[OFF_ENCB + tid];
    bM[tid] = ws[OFF_MIDB + tid];
    if (tid < 256) {  // x for t=0
        int r = tid >> 6, f = tid & 63;
        hcx[r][H2_ + f] = x_all[((b0 + r) * TE + 0) * F_ + f];
    }
    __syncthreads();

    const float4* WmT4   = (const float4*)(ws + OFF_WMT);     // [320][32] f4
    const float4* VdT4   = (const float4*)(ws + OFF_VdT);     // [128][16] f4
    const float4* eWihT4 = (const float4*)(ws + OFF_eWihT);   // [64][128] f4
    const float4* eWhhT4 = (const float4*)(ws + OFF_eWhhT);   // [128][128] f4
    const float4* mWihT4 = (const float4*)(ws + OFF_mWihT);   // [128][128] f4
    const float4* mWhhT4 = (const float4*)(ws + OFF_mWhhT);   // [128][128] f4
    const float4* WxT4   = (const float4*)(ws + OFF_WxT);     // [128][32] f4

    for (int t = 0; t < TE; ++t) {
        // ---- P1: m1 partials = [h|c|x] @ WmT   (thread = (cg32, ks16), 20 k each)
        {
            int cg = tid & 31, ks = tid >> 5;
            int k0 = ks * 20;
            float4 a0 = make_float4(0.f,0.f,0.f,0.f), a1 = a0, a2 = a0, a3 = a0;
            #pragma unroll
            for (int g = 0; g < 5; ++g) {
                int k = k0 + g * 4;
                GRP4(WmT4, 32, cg, k, hcx[0], hcx[1], hcx[2], hcx[3]);
            }
            float* sp = scratch + ks * 512 + cg * 4;
            *(float4*)(sp      ) = a0;
            *(float4*)(sp + 128) = a1;
            *(float4*)(sp + 256) = a2;
            *(float4*)(sp + 384) = a3;
        }
        __syncthreads();
        // P1c: combine 16 partials + bias + tanh -> av
        {
            int j = tid & 127, r = tid >> 7;
            const float* sp = scratch + r * 128 + j;
            float v = bWi[j];
            #pragma unroll
            for (int ks = 0; ks < 16; ++ks) v += sp[ks * 512];
            av[r][j] = tanh_fast(v);
        }
        __syncthreads();

        // ---- P3a: s partials = av @ VdT   (thread = (cg16, ks32), 4 k each)
        {
            int cg = tid & 15, ks = tid >> 4;
            int k0 = ks * 4;
            float4 a0 = make_float4(0.f,0.f,0.f,0.f), a1 = a0, a2 = a0, a3 = a0;
            GRP4(VdT4, 16, cg, k0, av[0], av[1], av[2], av[3]);
            float* sp = scratch + ks * 256 + cg * 4;
            *(float4*)(sp      ) = a0;
            *(float4*)(sp +  64) = a1;
            *(float4*)(sp + 128) = a2;
            *(float4*)(sp + 192) = a3;
        }
        __syncthreads();
        // P3b: combine 32 + softmax over 64 -> xin (waves 0-3); waves 4-7 prefetch x_{t+1}
        if (tid < 256) {
            int j = tid & 63, r = tid >> 6;
            const float* sp = scratch + r * 64 + j;
            float acc = bVd[j];
            #pragma unroll
            for (int ks = 0; ks < 32; ++ks) acc += sp[ks * 256];
            float m = acc;
            for (int off = 32; off > 0; off >>= 1) m = fmaxf(m, __shfl_xor(m, off, 64));
            float e = fexp2((acc - m) * LOG2E);
            float ssum = e;
            for (int off = 32; off > 0; off >>= 1) ssum += __shfl_xor(ssum, off, 64);
            xin[r][j] = hcx[r][H2_ + j] * e * frcp(ssum);
        } else if (t + 1 < TE) {
            int q = tid - 256, r = q >> 6, f = q & 63;
            xnext[r][f] = x_all[((b0 + r) * TE + (t + 1)) * F_ + f];
        }
        __syncthreads();

        // ---- P4: enc gate partials = xin@eWih (K=64) + h@eWhh (K=128)  (thread = (cg128, ks4))
        {
            int cg = tid & 127, ks = tid >> 7;
            float4 a0 = make_float4(0.f,0.f,0.f,0.f), a1 = a0, a2 = a0, a3 = a0;
            int ka = ks * 16;
            #pragma unroll
            for (int g = 0; g < 4; ++g) {
                int k = ka + g * 4;
                GRP4(eWihT4, 128, cg, k, xin[0], xin[1], xin[2], xin[3]);
            }
            int kb = ks * 32;
            #pragma unroll 4
            for (int g = 0; g < 8; ++g) {
                int k = kb + g * 4;
                GRP4(eWhhT4, 128, cg, k, hcx[0], hcx[1], hcx[2], hcx[3]);
            }
            float* sp = scratch + ks * 2048 + cg * 4;
            *(float4*)(sp       ) = a0;
            *(float4*)(sp +  512) = a1;
            *(float4*)(sp + 1024) = a2;
            *(float4*)(sp + 1536) = a3;
        }
        __syncthreads();
        // P4c: combine 4 partials/gate + enc LSTM cell; threads 0-255 install prefetched x
        {
            int j = tid & 127, r = tid >> 7;
            const float* sp = scratch + r * 512;
            float gi = bE[j], gf = bE[j + 128], gg = bE[j + 256], go = bE[j + 384];
            #pragma unroll
            for (int ks = 0; ks < 4; ++ks) {
                const float* p = sp + ks * 2048;
                gi += p[j]; gf += p[j + 128]; gg += p[j + 256]; go += p[j + 384];
            }
            float c = sigm(gf) * hcx[r][H_ + j] + sigm(gi) * tanh_fast(gg);
            float h = sigm(go) * tanh_fast(c);
            hcx[r][H_ + j] = c; hcx[r][j] = h;
            if (tid < 256 && t + 1 < TE) {
                int rr = tid >> 6, f = tid & 63;
                hcx[rr][H2_ + f] = xnext[rr][f];
            }
        }
        __syncthreads();

        // ---- P6: mid gate partials = h_enc@mWih (K=128) + h_mid@mWhh (K=128)
        {
            int cg = tid & 127, ks = tid >> 7;
            float4 a0 = make_float4(0.f,0.f,0.f,0.f), a1 = a0, a2 = a0, a3 = a0;
            int kb = ks * 32;
            #pragma unroll 4
            for (int g = 0; g < 8; ++g) {
                int k = kb + g * 4;
                GRP4(mWihT4, 128, cg, k, hcx[0], hcx[1], hcx[2], hcx[3]);
            }
            #pragma unroll 4
            for (int g = 0; g < 8; ++g) {
                int k = kb + g * 4;
                GRP4(mWhhT4, 128, cg, k, hm[0], hm[1], hm[2], hm[3]);
            }
            float* sp = scratch + ks * 2048 + cg * 4;
            *(float4*)(sp       ) = a0;
            *(float4*)(sp +  512) = a1;
            *(float4*)(sp + 1024) = a2;
            *(float4*)(sp + 1536) = a3;
        }
        __syncthreads();
        // P6c: combine + mid LSTM cell + store mid_out
        {
            int j = tid & 127, r = tid >> 7;
            const float* sp = scratch + r * 512;
            float gi = bM[j], gf = bM[j + 128], gg = bM[j + 256], go = bM[j + 384];
            #pragma unroll
            for (int ks = 0; ks < 4; ++ks) {
                const float* p = sp + ks * 2048;
                gi += p[j]; gf += p[j + 128]; gg += p[j + 256]; go += p[j + 384];
            }
            float c = sigm(gf) * cm[r][j] + sigm(gi) * tanh_fast(gg);
            float h = sigm(go) * tanh_fast(c);
            cm[r][j] = c; hm[r][j] = h;
            ws[OFF_MID + ((size_t)(b0 + r) * TE + t) * H_ + j] = h;
        }
        __syncthreads();

        // ---- P8: wx partials = h_mid @ WxT   (thread = (cg32, ks16), 8 k each)
        {
            int cg = tid & 31, ks = tid >> 5;
            int k0 = ks * 8;
            float4 a0 = make_float4(0.f,0.f,0.f,0.f), a1 = a0, a2 = a0, a3 = a0;
            #pragma unroll
            for (int g = 0; g < 2; ++g) {
                int k = k0 + g * 4;
                GRP4(WxT4, 32, cg, k, hm[0], hm[1], hm[2], hm[3]);
            }
            float* sp = scratch + ks * 512 + cg * 4;
            *(float4*)(sp      ) = a0;
            *(float4*)(sp + 128) = a1;
            *(float4*)(sp + 256) = a2;
            *(float4*)(sp + 384) = a3;
        }
        __syncthreads();
        // P8c: combine + store wx
        {
            int j = tid & 127, r = tid >> 7;
            const float* sp = scratch + r * 128 + j;
            float v = bWx[j];
            #pragma unroll
            for (int ks = 0; ks < 16; ++ks) v += sp[ks * 512];
            ws[OFF_WX + ((size_t)(b0 + r) * TE + t) * H_ + j] = v;
        }
        __syncthreads();   // scratch reused by next-step P1
    }

    {
        int j = tid & 127, r = tid >> 7;
        ws[OFF_STH + (b0 + r) * H_ + j] = hm[r][j];
        ws[OFF_STC + (b0 + r) * H_ + j] = cm[r][j];
    }
}

// ---------------- persistent decoder: 512 blocks x 512 thr, 2 rows/block ----------------
#define QP_ 132   // padded qv row stride (f4-aligned, breaks power-of-2 conflicts)

__global__ __launch_bounds__(512, 2) void dec_kernel(
    const float* __restrict__ Vw_in,
    const float* __restrict__ Vb_in,
    const float* __restrict__ rw_in,
    const float* __restrict__ rb_in,
    const float* __restrict__ ws,
    float* __restrict__ out)
{
    __shared__ __align__(16) float hc2[2][H2_];      // [hi | ci]
    __shared__ __align__(16) float qv[2][QP_];       // q, then reused as dec_in
    __shared__ __align__(16) float qp[4][2][H_];     // q k-split partials
    __shared__ __align__(16) float sb[2][TE];
    __shared__ __align__(16) float dinp[8][2][H_];   // dec_in tp-split partials
    __shared__ __align__(16) float gp[4][2][G_];     // gate k-split partials
    __shared__ float bD[G_], Vw[H_], rw[H_];

    const int tid = threadIdx.x;
    const int b0  = blockIdx.x * 2;
    const float Vb = Vb_in[0], rb = rb_in[0];

    {
        int r = tid >> 8, c = tid & 255;
        hc2[r][c] = (c < H_) ? ws[OFF_STH + (b0 + r) * H_ + c]
                             : ws[OFF_STC + (b0 + r) * H_ + (c - H_)];
    }
    if (tid < H_) { Vw[tid] = Vw_in[tid]; rw[tid] = rw_in[tid]; }
    bD[tid] = ws[OFF_DECB + tid];
    __syncthreads();

    const float*  WhT    = ws + OFF_WhT;                      // [256][128]
    const float4* dWihT4 = (const float4*)(ws + OFF_dWihT);   // [128][128] f4
    const float4* dWhhT4 = (const float4*)(ws + OFF_dWhhT);   // [128][128] f4
    const float4* wx4    = (const float4*)(ws + OFF_WX);
    const float4* mid4   = (const float4*)(ws + OFF_MID);

    for (int td = 0; td < TD; ++td) {
        // P1: q partials = [hi|ci]@WhT  (thread = (j128, ks4), 64 k each, both rows)
        {
            int j = tid & 127, ks = tid >> 7;
            int k0 = ks * 64;
            float a00 = 0.f, a01 = 0.f, a10 = 0.f, a11 = 0.f;
            #pragma unroll 8
            for (int k = k0; k < k0 + 64; k += 2) {
                float w0 = WhT[(k    ) * H_ + j];
                float w1 = WhT[(k + 1) * H_ + j];
                a00 += w0 * hc2[0][k];     a10 += w0 * hc2[1][k];
                a01 += w1 * hc2[0][k + 1]; a11 += w1 * hc2[1][k + 1];
            }
            qp[ks][0][j] = a00 + a01;
            qp[ks][1][j] = a10 + a11;
        }
        __syncthreads();
        // P1b: combine
        if (tid < 256) {
            int j = tid & 127, r = tid >> 7;
            qv[r][j] = (qp[0][r][j] + qp[1][r][j]) + (qp[2][r][j] + qp[3][r][j]);
        }
        __syncthreads();

        // P2: scores sb[r][tp] = sum_h tanh(q[r][h] + wx[b][tp][h]) * Vw[h] + Vb
        for (int task = tid; task < 2 * TE; task += 512) {
            int r = (task >= TE) ? 1 : 0;
            int tp = task - r * TE;
            const float4* wxr = wx4 + ((size_t)(b0 + r) * TE + tp) * (H_ / 4);
            float acc = Vb;
            #pragma unroll 8
            for (int kk = 0; kk < H_ / 4; ++kk) {
                float4 wv = wxr[kk];
                float4 qq = *(const float4*)&qv[r][kk * 4];
                float4 vv = *(const float4*)&Vw[kk * 4];
                acc += tanh_fast(qq.x + wv.x) * vv.x;
                acc += tanh_fast(qq.y + wv.y) * vv.y;
                acc += tanh_fast(qq.z + wv.z) * vv.z;
                acc += tanh_fast(qq.w + wv.w) * vv.w;
            }
            sb[r][tp] = acc;
        }
        __syncthreads();

        // P3: dec_in partials over tp chunks of 21  (thread = (cg32, r2, ts8))
        {
            int ts = tid >> 6, r = (tid >> 5) & 1, cg = tid & 31;
            int t0 = ts * 21;
            float4 a = make_float4(0.f, 0.f, 0.f, 0.f);
            #pragma unroll 3
            for (int tp = t0; tp < t0 + 21; ++tp) {
                float s = sb[r][tp];
                float4 m = mid4[((size_t)(b0 + r) * TE + tp) * 32 + cg];
                fma4(a, m, s);
            }
            *(float4*)&dinp[ts][r][cg * 4] = a;
        }
        __syncthreads();
        // P3b: combine into qv (reused as dec_in)
        if (tid < 256) {
            int j = tid & 127, r = tid >> 7;
            qv[r][j] = ((dinp[0][r][j] + dinp[1][r][j]) + (dinp[2][r][j] + dinp[3][r][j]))
                     + ((dinp[4][r][j] + dinp[5][r][j]) + (dinp[6][r][j] + dinp[7][r][j]));
        }
        __syncthreads();

        // P4: gate partials = dec_in@dWih + hi@dWhh  (thread = (cg128, ks4), weights once, 2 rows)
        {
            int cg = tid & 127, ks = tid >> 7;
            int kb = ks * 32;
            float4 a0 = make_float4(0.f,0.f,0.f,0.f), a1 = a0;
            #pragma unroll 4
            for (int g = 0; g < 8; ++g) {
                int k = kb + g * 4;
                float4 wv0 = dWihT4[(k + 0) * 128 + cg];
                float4 wv1 = dWihT4[(k + 1) * 128 + cg];
                float4 wv2 = dWihT4[(k + 2) * 128 + cg];
                float4 wv3 = dWihT4[(k + 3) * 128 + cg];
                float4 xv0 = *(const float4*)&qv[0][k];
                float4 xv1 = *(const float4*)&qv[1][k];
                fma4(a0, wv0, xv0.x); fma4(a0, wv1, xv0.y); fma4(a0, wv2, xv0.z); fma4(a0, wv3, xv0.w);
                fma4(a1, wv0, xv1.x); fma4(a1, wv1, xv1.y); fma4(a1, wv2, xv1.z); fma4(a1, wv3, xv1.w);
            }
            #pragma unroll 4
            for (int g = 0; g < 8; ++g) {
                int k = kb + g * 4;
                float4 wv0 = dWhhT4[(k + 0) * 128 + cg];
                float4 wv1 = dWhhT4[(k + 1) * 128 + cg];
                float4 wv2 = dWhhT4[(k + 2) * 128 + cg];
                float4 wv3 = dWhhT4[(k + 3) * 128 + cg];
                float4 xv0 = *(const float4*)&hc2[0][k];
                float4 xv1 = *(const float4*)&hc2[1][k];
                fma4(a0, wv0, xv0.x); fma4(a0, wv1, xv0.y); fma4(a0, wv2, xv0.z); fma4(a0, wv3, xv0.w);
                fma4(a1, wv0, xv1.x); fma4(a1, wv1, xv1.y); fma4(a1, wv2, xv1.z); fma4(a1, wv3, xv1.w);
            }
            *(float4*)&gp[ks][0][cg * 4] = a0;
            *(float4*)&gp[ks][1][cg * 4] = a1;
        }
        __syncthreads();

        // P5: combine + LSTM update (threads 0-255)
        if (tid < 256) {
            int j = tid & 127, r = tid >> 7;
            float gi = bD[j], gf = bD[j + 128], gg = bD[j + 256], go = bD[j + 384];
            #pragma unroll
            for (int ks = 0; ks < 4; ++ks) {
                const float* p = gp[ks][r];
                gi += p[j]; gf += p[j + 128]; gg += p[j + 256]; go += p[j + 384];
            }
            float c = sigm(gf) * hc2[r][H_ + j] + sigm(gi) * tanh_fast(gg);
            float h = sigm(go) * tanh_fast(c);
            hc2[r][H_ + j] = c; hc2[r][j] = h;
        }
        __syncthreads();

        // P6: out[b][td] = h . reg_w + reg_b  (2 waves; no trailing barrier needed:
        // next P1 writes qp [last read P1b] and only reads hc2)
        if (tid < 128) {
            int r = tid >> 6, lane = tid & 63;
            float v = hc2[r][lane] * rw[lane] + hc2[r][lane + 64] * rw[lane + 64];
            for (int off = 32; off > 0; off >>= 1) v += __shfl_xor(v, off, 64);
            if (lane == 0) out[(b0 + r) * TD + td] = v + rb;
        }
    }
}

extern "C" void kernel_launch(void* const* d_in, const int* in_sizes, int n_in,
                              void* d_out, int out_size, void* d_ws, size_t ws_size,
                              hipStream_t stream)
{
    (void)in_sizes; (void)n_in; (void)out_size;
    if (ws_size < (size_t)WS_FLOATS * sizeof(float)) return;

    const float* x_all = (const float*)d_in[0];
    const float* Wi_b  = (const float*)d_in[3];
    const float* Vd_b  = (const float*)d_in[6];
    const float* Wx_b  = (const float*)d_in[16];
    const float* V_w   = (const float*)d_in[18];
    const float* V_b   = (const float*)d_in[19];
    const float* reg_w = (const float*)d_in[24];
    const float* reg_b = (const float*)d_in[25];
    float* ws  = (float*)d_ws;
    float* out = (float*)d_out;

    PrepArgs pa{
        (const float*)d_in[4],  // We_w
        (const float*)d_in[2],  // Wi_w
        (const float*)d_in[5],  // Vd_w
        (const float*)d_in[7],  // enc_Wih
        (const float*)d_in[8],  // enc_Whh
        (const float*)d_in[9],  // enc_bih
        (const float*)d_in[10], // enc_bhh
        (const float*)d_in[11], // mid_Wih
        (const float*)d_in[12], // mid_Whh
        (const float*)d_in[13], // mid_bih
        (const float*)d_in[14], // mid_bhh
        (const float*)d_in[15], // Wx_w
        (const float*)d_in[17], // Wh_w
        (const float*)d_in[20], // dec_Wih
        (const float*)d_in[21], // dec_Whh
        (const float*)d_in[22], // dec_bih
        (const float*)d_in[23]  // dec_bhh
    };

    prep_kernel<<<56, 256, 0, stream>>>(pa, ws);
    enc_mid_kernel<<<256, 512, 0, stream>>>(x_all, Wi_b, Vd_b, Wx_b, ws);
    dec_kernel<<<512, 512, 0, stream>>>(V_w, V_b, reg_w, reg_b, ws, out);
}

// Round 9
// 2738.094 us; speedup vs baseline: 5.6120x; 1.0948x over previous
//
#include <hip/hip_runtime.h>

#define B_   1024
#define TE   168
#define TD   24
#define F_   64
#define H_   128
#define H2_  256
#define G_   512
#define KM_  320   // combined [h|c|x] K for m1

// ---- workspace float offsets (half arrays reuse the same slots, half the bytes) ----
#define OFF_WMT    0          // half [320][128]
#define OFF_VdT    40960      // float [128][64]
#define OFF_eWihT  49152      // half [64][512]
#define OFF_eWhhT  81920      // half [128][512]
#define OFF_mWihT  147456     // half [128][512]
#define OFF_mWhhT  212992     // half [128][512]
#define OFF_WxT    278528     // half [128][128]
#define OFF_WhT    294912     // half [256][128]
#define OFF_dWihT  327680     // half [128][512]
#define OFF_dWhhT  393216     // half [128][512]
#define OFF_ENCB   458752     // float [512] bih+bhh
#define OFF_MIDB   459264
#define OFF_DECB   459776
#define OFF_MID    460800                      // half [1024][168][128]
#define OFF_WX     (OFF_MID + B_*TE*H_)        // half [1024][168][128]
#define OFF_STH    (OFF_WX  + B_*TE*H_)        // float [1024][128]
#define OFF_STC    (OFF_STH + B_*H_)
#define WS_FLOATS  (OFF_STC + B_*H_)

typedef _Float16 half8 __attribute__((ext_vector_type(8)));
typedef _Float16 half4 __attribute__((ext_vector_type(4)));

__device__ __forceinline__ float fexp2(float x) { return __builtin_amdgcn_exp2f(x); }
__device__ __forceinline__ float frcp(float x)  { return __builtin_amdgcn_rcpf(x); }
#define LOG2E 1.4426950408889634f

__device__ __forceinline__ float sigm(float x) {
    return frcp(1.f + fexp2(-LOG2E * x));
}
__device__ __forceinline__ float tanh_fast(float x) {
    float e = fexp2(2.f * LOG2E * x);
    return 1.f - 2.f * frcp(e + 1.f);
}

__device__ __forceinline__ void fma4(float4& g, const float4 wv, const float s) {
    g.x = __builtin_fmaf(wv.x, s, g.x);
    g.y = __builtin_fmaf(wv.y, s, g.y);
    g.z = __builtin_fmaf(wv.z, s, g.z);
    g.w = __builtin_fmaf(wv.w, s, g.w);
}
__device__ __forceinline__ void unpack8(const half8 h, float4& lo, float4& hi) {
    lo.x = (float)h[0]; lo.y = (float)h[1]; lo.z = (float)h[2]; lo.w = (float)h[3];
    hi.x = (float)h[4]; hi.y = (float)h[5]; hi.z = (float)h[6]; hi.w = (float)h[7];
}

// fp32 4-k group (used for VdT only)
#define GRP4(WT, STRIDE, CGV, KK, A0, A1, A2, A3)                         \
    {                                                                     \
        float4 wv0 = WT[(KK + 0) * STRIDE + CGV];                         \
        float4 wv1 = WT[(KK + 1) * STRIDE + CGV];                         \
        float4 wv2 = WT[(KK + 2) * STRIDE + CGV];                         \
        float4 wv3 = WT[(KK + 3) * STRIDE + CGV];                         \
        float4 xv0 = *(const float4*)&A0[KK];                             \
        float4 xv1 = *(const float4*)&A1[KK];                             \
        float4 xv2 = *(const float4*)&A2[KK];                             \
        float4 xv3 = *(const float4*)&A3[KK];                             \
        fma4(a0, wv0, xv0.x); fma4(a0, wv1, xv0.y); fma4(a0, wv2, xv0.z); fma4(a0, wv3, xv0.w); \
        fma4(a1, wv0, xv1.x); fma4(a1, wv1, xv1.y); fma4(a1, wv2, xv1.z); fma4(a1, wv3, xv1.w); \
        fma4(a2, wv0, xv2.x); fma4(a2, wv1, xv2.y); fma4(a2, wv2, xv2.z); fma4(a2, wv3, xv2.w); \
        fma4(a3, wv0, xv3.x); fma4(a3, wv1, xv3.y); fma4(a3, wv2, xv3.z); fma4(a3, wv3, xv3.w); \
    }

// 8 fma4: one half8 (8 cols) x 4-row activation vector into 8 accumulators
#define HGRP(HV, XV)                                                      \
    {                                                                     \
        float4 lo, hi; unpack8(HV, lo, hi);                               \
        fma4(a00, lo, XV.x); fma4(a01, hi, XV.x);                         \
        fma4(a10, lo, XV.y); fma4(a11, hi, XV.y);                         \
        fma4(a20, lo, XV.z); fma4(a21, hi, XV.z);                         \
        fma4(a30, lo, XV.w); fma4(a31, hi, XV.w);                         \
    }

// ---------------- prep: transpose weights to [K][N] (fp16 for streamed ones), sum bias pairs ----------------
struct PrepArgs {
    const float *We, *Wi, *Vd, *eWih, *eWhh, *eBih, *eBhh,
                *mWih, *mWhh, *mBih, *mBhh, *Wx, *Wh, *dWih, *dWhh, *dBih, *dBhh;
};

__global__ void prep_kernel(PrepArgs a, float* __restrict__ ws) {
    int sec  = blockIdx.x >> 2;
    int base = (blockIdx.x & 3) * blockDim.x + threadIdx.x;
    const int stride = blockDim.x * 4;
    const float* src = nullptr; int R = 0, C = 0, off = 0, hoffe = 0, ishalf = 1;
    switch (sec) {
        case 0:  src = a.We;   R = 128; C = 256; off = OFF_WMT;   hoffe = 0;     break;
        case 1:  src = a.Wi;   R = 128; C = 64;  off = OFF_WMT;   hoffe = 32768; break;
        case 2:  src = a.Vd;   R = 64;  C = 128; off = OFF_VdT;   ishalf = 0;    break;
        case 3:  src = a.eWih; R = 512; C = 64;  off = OFF_eWihT; break;
        case 4:  src = a.eWhh; R = 512; C = 128; off = OFF_eWhhT; break;
        case 5:  src = a.mWih; R = 512; C = 128; off = OFF_mWihT; break;
        case 6:  src = a.mWhh; R = 512; C = 128; off = OFF_mWhhT; break;
        case 7:  src = a.Wx;   R = 128; C = 128; off = OFF_WxT;   break;
        case 8:  src = a.Wh;   R = 128; C = 256; off = OFF_WhT;   break;
        case 9:  src = a.dWih; R = 512; C = 128; off = OFF_dWihT; break;
        case 10: src = a.dWhh; R = 512; C = 128; off = OFF_dWhhT; break;
        case 11: for (int i = base; i < 512; i += stride) ws[OFF_ENCB + i] = a.eBih[i] + a.eBhh[i]; return;
        case 12: for (int i = base; i < 512; i += stride) ws[OFF_MIDB + i] = a.mBih[i] + a.mBhh[i]; return;
        case 13: for (int i = base; i < 512; i += stride) ws[OFF_DECB + i] = a.dBih[i] + a.dBhh[i]; return;
        default: return;
    }
    int n = R * C;
    int rmask  = R - 1;
    int rshift = (R == 512) ? 9 : ((R == 128) ? 7 : 6);
    if (ishalf) {
        _Float16* hd = (_Float16*)(ws + off) + hoffe;
        for (int o = base; o < n; o += stride) {
            int r = o & rmask, c = o >> rshift;
            hd[o] = (_Float16)src[r * C + c];
        }
    } else {
        for (int o = base; o < n; o += stride) {
            int r = o & rmask, c = o >> rshift;
            ws[off + o] = src[r * C + c];
        }
    }
}

// ---------------- persistent encoder + mid LSTM: 256 blocks x 512 thr, 4 rows/block ----------------
// fp16 weight stream read once per block per step; activations in transposed LDS [k][4 rows].
__global__ __launch_bounds__(512, 1) void enc_mid_kernel(
    const float* __restrict__ x_all,   // [B][Te][F]
    const float* __restrict__ Wi_b,
    const float* __restrict__ Vd_b,
    const float* __restrict__ Wx_b,
    float* __restrict__ ws)
{
    __shared__ __align__(16) float scratch[16384];   // 64KB k-split partials (time-disjoint)
    __shared__ __align__(16) float hcxT[KM_][4];     // [k][row]: h(0..127) | c(128..255) | x(256..319)
    __shared__ __align__(16) float hmT[H_][4];       // mid h, [k][row]
    __shared__ __align__(16) float cmv[4][H_];       // mid c
    __shared__ __align__(16) float xinT[F_][4];      // attention-weighted x, [k][row]
    __shared__ __align__(16) float xnext[4][F_];
    __shared__ __align__(16) float av[4][H_];
    __shared__ float bWi[H_], bVd[F_], bWx[H_], bE[G_], bM[G_];

    const int tid = threadIdx.x;
    const int b0  = blockIdx.x * 4;

    for (int i = tid; i < KM_ * 4; i += 512) ((float*)hcxT)[i] = 0.f;
    ((float*)hmT)[tid] = 0.f; ((float*)cmv)[tid] = 0.f;
    if (tid < H_) { bWi[tid] = Wi_b[tid]; bWx[tid] = Wx_b[tid]; }
    if (tid < F_) bVd[tid] = Vd_b[tid];
    bE[tid] = ws[OFF_ENCB + tid];
    bM[tid] = ws[OFF_MIDB + tid];
    if (tid < 256) {  // x for t=0
        int r = tid >> 6, f = tid & 63;
        hcxT[H2_ + f][r] = x_all[((b0 + r) * TE + 0) * F_ + f];
    }
    __syncthreads();

    const half8*  WmH  = (const half8*)(ws + OFF_WMT);     // [320][16]
    const float4* VdT4 = (const float4*)(ws + OFF_VdT);    // [128][16] f4
    const half8*  eWih = (const half8*)(ws + OFF_eWihT);   // [64][64]
    const half8*  eWhh = (const half8*)(ws + OFF_eWhhT);   // [128][64]
    const half8*  mWih = (const half8*)(ws + OFF_mWihT);   // [128][64]
    const half8*  mWhh = (const half8*)(ws + OFF_mWhhT);   // [128][64]
    const half8*  WxH  = (const half8*)(ws + OFF_WxT);     // [128][16]
    _Float16* midH = (_Float16*)(ws + OFF_MID);
    _Float16* wxH  = (_Float16*)(ws + OFF_WX);

    for (int t = 0; t < TE; ++t) {
        // ---- P1: m1 partials = [h|c|x] @ WmT  (thread = (cg16 x 8cols, ks32), 10 k each)
        {
            int cg = tid & 15, ks = tid >> 4;
            int k0 = ks * 10;
            float4 a00 = make_float4(0.f,0.f,0.f,0.f), a01 = a00, a10 = a00, a11 = a00,
                   a20 = a00, a21 = a00, a30 = a00, a31 = a00;
            #pragma unroll 5
            for (int k = k0; k < k0 + 10; ++k) {
                half8 hv = WmH[k * 16 + cg];
                float4 xv = *(const float4*)&hcxT[k][0];
                HGRP(hv, xv);
            }
            float* sp = scratch + ks * 512 + cg * 8;
            *(float4*)(sp      ) = a00; *(float4*)(sp +   4) = a01;
            *(float4*)(sp + 128) = a10; *(float4*)(sp + 132) = a11;
            *(float4*)(sp + 256) = a20; *(float4*)(sp + 260) = a21;
            *(float4*)(sp + 384) = a30; *(float4*)(sp + 388) = a31;
        }
        __syncthreads();
        // P1c: combine 32 + bias + tanh -> av
        {
            int j = tid & 127, r = tid >> 7;
            const float* sp = scratch + r * 128 + j;
            float v = bWi[j];
            #pragma unroll
            for (int ks = 0; ks < 32; ++ks) v += sp[ks * 512];
            av[r][j] = tanh_fast(v);
        }
        __syncthreads();

        // ---- P3a: s partials = av @ VdT (fp32, thread = (cg16 x 4cols, ks32), 4 k each)
        {
            int cg = tid & 15, ks = tid >> 4;
            int k0 = ks * 4;
            float4 a0 = make_float4(0.f,0.f,0.f,0.f), a1 = a0, a2 = a0, a3 = a0;
            GRP4(VdT4, 16, cg, k0, av[0], av[1], av[2], av[3]);
            float* sp = scratch + ks * 256 + cg * 4;
            *(float4*)(sp      ) = a0;
            *(float4*)(sp +  64) = a1;
            *(float4*)(sp + 128) = a2;
            *(float4*)(sp + 192) = a3;
        }
        __syncthreads();
        // P3b: combine 32 + softmax over 64 -> xinT; waves 4-7 prefetch x_{t+1}
        if (tid < 256) {
            int j = tid & 63, r = tid >> 6;
            const float* sp = scratch + r * 64 + j;
            float acc = bVd[j];
            #pragma unroll
            for (int ks = 0; ks < 32; ++ks) acc += sp[ks * 256];
            float m = acc;
            for (int off = 32; off > 0; off >>= 1) m = fmaxf(m, __shfl_xor(m, off, 64));
            float e = fexp2((acc - m) * LOG2E);
            float ssum = e;
            for (int off = 32; off > 0; off >>= 1) ssum += __shfl_xor(ssum, off, 64);
            xinT[j][r] = hcxT[H2_ + j][r] * e * frcp(ssum);
        } else if (t + 1 < TE) {
            int q = tid - 256, r = q >> 6, f = q & 63;
            xnext[r][f] = x_all[((b0 + r) * TE + (t + 1)) * F_ + f];
        }
        __syncthreads();

        // ---- P4: enc gate partials = xin@eWih (K=64) + h@eWhh (K=128)  (thread = (cg64 x 8cols, ks8))
        {
            int cg = tid & 63, ks = tid >> 6;
            float4 a00 = make_float4(0.f,0.f,0.f,0.f), a01 = a00, a10 = a00, a11 = a00,
                   a20 = a00, a21 = a00, a30 = a00, a31 = a00;
            int ka = ks * 8;
            #pragma unroll 4
            for (int k = ka; k < ka + 8; ++k) {
                half8 hv = eWih[k * 64 + cg];
                float4 xv = *(const float4*)&xinT[k][0];
                HGRP(hv, xv);
            }
            int kb = ks * 16;
            #pragma unroll 4
            for (int k = kb; k < kb + 16; ++k) {
                half8 hv = eWhh[k * 64 + cg];
                float4 xv = *(const float4*)&hcxT[k][0];
                HGRP(hv, xv);
            }
            float* sp = scratch + ks * 2048 + cg * 8;
            *(float4*)(sp       ) = a00; *(float4*)(sp +    4) = a01;
            *(float4*)(sp +  512) = a10; *(float4*)(sp +  516) = a11;
            *(float4*)(sp + 1024) = a20; *(float4*)(sp + 1028) = a21;
            *(float4*)(sp + 1536) = a30; *(float4*)(sp + 1540) = a31;
        }
        __syncthreads();
        // P4c: combine 8/gate + enc LSTM cell; threads 0-255 install prefetched x
        {
            int j = tid & 127, r = tid >> 7;
            const float* sp = scratch + r * 512;
            float gi = bE[j], gf = bE[j + 128], gg = bE[j + 256], go = bE[j + 384];
            #pragma unroll
            for (int ks = 0; ks < 8; ++ks) {
                const float* p = sp + ks * 2048;
                gi += p[j]; gf += p[j + 128]; gg += p[j + 256]; go += p[j + 384];
            }
            float c = sigm(gf) * hcxT[H_ + j][r] + sigm(gi) * tanh_fast(gg);
            float h = sigm(go) * tanh_fast(c);
            hcxT[H_ + j][r] = c; hcxT[j][r] = h;
            if (tid < 256 && t + 1 < TE) {
                int rr = tid >> 6, f = tid & 63;
                hcxT[H2_ + f][rr] = xnext[rr][f];
            }
        }
        __syncthreads();

        // ---- P6: mid gate partials = h_enc@mWih + h_mid@mWhh  (both K=128)
        {
            int cg = tid & 63, ks = tid >> 6;
            float4 a00 = make_float4(0.f,0.f,0.f,0.f), a01 = a00, a10 = a00, a11 = a00,
                   a20 = a00, a21 = a00, a30 = a00, a31 = a00;
            int kb = ks * 16;
            #pragma unroll 4
            for (int k = kb; k < kb + 16; ++k) {
                half8 hv = mWih[k * 64 + cg];
                float4 xv = *(const float4*)&hcxT[k][0];
                HGRP(hv, xv);
            }
            #pragma unroll 4
            for (int k = kb; k < kb + 16; ++k) {
                half8 hv = mWhh[k * 64 + cg];
                float4 xv = *(const float4*)&hmT[k][0];
                HGRP(hv, xv);
            }
            float* sp = scratch + ks * 2048 + cg * 8;
            *(float4*)(sp       ) = a00; *(float4*)(sp +    4) = a01;
            *(float4*)(sp +  512) = a10; *(float4*)(sp +  516) = a11;
            *(float4*)(sp + 1024) = a20; *(float4*)(sp + 1028) = a21;
            *(float4*)(sp + 1536) = a30; *(float4*)(sp + 1540) = a31;
        }
        __syncthreads();
        // P6c: combine + mid LSTM cell + store mid_out (fp16)
        {
            int j = tid & 127, r = tid >> 7;
            const float* sp = scratch + r * 512;
            float gi = bM[j], gf = bM[j + 128], gg = bM[j + 256], go = bM[j + 384];
            #pragma unroll
            for (int ks = 0; ks < 8; ++ks) {
                const float* p = sp + ks * 2048;
                gi += p[j]; gf += p[j + 128]; gg += p[j + 256]; go += p[j + 384];
            }
            float c = sigm(gf) * cmv[r][j] + sigm(gi) * tanh_fast(gg);
            float h = sigm(go) * tanh_fast(c);
            cmv[r][j] = c; hmT[j][r] = h;
            midH[((size_t)(b0 + r) * TE + t) * H_ + j] = (_Float16)h;
        }
        __syncthreads();

        // ---- P8: wx partials = h_mid @ WxT  (thread = (cg16 x 8cols, ks32), 4 k each)
        {
            int cg = tid & 15, ks = tid >> 4;
            int k0 = ks * 4;
            float4 a00 = make_float4(0.f,0.f,0.f,0.f), a01 = a00, a10 = a00, a11 = a00,
                   a20 = a00, a21 = a00, a30 = a00, a31 = a00;
            #pragma unroll
            for (int k = k0; k < k0 + 4; ++k) {
                half8 hv = WxH[k * 16 + cg];
                float4 xv = *(const float4*)&hmT[k][0];
                HGRP(hv, xv);
            }
            float* sp = scratch + ks * 512 + cg * 8;
            *(float4*)(sp      ) = a00; *(float4*)(sp +   4) = a01;
            *(float4*)(sp + 128) = a10; *(float4*)(sp + 132) = a11;
            *(float4*)(sp + 256) = a20; *(float4*)(sp + 260) = a21;
            *(float4*)(sp + 384) = a30; *(float4*)(sp + 388) = a31;
        }
        __syncthreads();
        // P8c: combine + store wx (fp16)
        {
            int j = tid & 127, r = tid >> 7;
            const float* sp = scratch + r * 128 + j;
            float v = bWx[j];
            #pragma unroll
            for (int ks = 0; ks < 32; ++ks) v += sp[ks * 512];
            wxH[((size_t)(b0 + r) * TE + t) * H_ + j] = (_Float16)v;
        }
        __syncthreads();   // scratch reused by next-step P1
    }

    {
        int j = tid & 127, r = tid >> 7;
        ws[OFF_STH + (b0 + r) * H_ + j] = hmT[j][r];
        ws[OFF_STC + (b0 + r) * H_ + j] = cmv[r][j];
    }
}

// ---------------- persistent decoder: 512 blocks x 512 thr, 2 rows/block ----------------
#define QP_ 132

__global__ __launch_bounds__(512, 2) void dec_kernel(
    const float* __restrict__ Vw_in,
    const float* __restrict__ Vb_in,
    const float* __restrict__ rw_in,
    const float* __restrict__ rb_in,
    const float* __restrict__ ws,
    float* __restrict__ out)
{
    __shared__ __align__(16) float scr[8192];        // 32KB: qp[32][2][128] / gp[8][2][512] time-disjoint
    __shared__ __align__(16) float hc2[2][H2_];      // [hi | ci]
    __shared__ __align__(16) float qv[2][QP_];       // q, then reused as dec_in
    __shared__ __align__(16) float sb[2][TE];
    __shared__ __align__(16) float dinp[8][2][H_];   // dec_in tp-split partials
    __shared__ float bD[G_], Vw[H_], rw[H_];

    const int tid = threadIdx.x;
    const int b0  = blockIdx.x * 2;
    const float Vb = Vb_in[0], rb = rb_in[0];

    {
        int r = tid >> 8, c = tid & 255;
        hc2[r][c] = (c < H_) ? ws[OFF_STH + (b0 + r) * H_ + c]
                             : ws[OFF_STC + (b0 + r) * H_ + (c - H_)];
    }
    if (tid < H_) { Vw[tid] = Vw_in[tid]; rw[tid] = rw_in[tid]; }
    bD[tid] = ws[OFF_DECB + tid];
    __syncthreads();

    const half8* WhH  = (const half8*)(ws + OFF_WhT);     // [256][16]
    const half8* dWih = (const half8*)(ws + OFF_dWihT);   // [128][64]
    const half8* dWhh = (const half8*)(ws + OFF_dWhhT);   // [128][64]
    const half8* wx8  = (const half8*)(ws + OFF_WX);
    const half4* mid4 = (const half4*)(ws + OFF_MID);

    for (int td = 0; td < TD; ++td) {
        // P1: q partials = [hi|ci]@WhT  (thread = (cg16 x 8cols, ks32), 8 k each, both rows)
        {
            int cg = tid & 15, ks = tid >> 4;
            int k0 = ks * 8;
            float4 a00 = make_float4(0.f,0.f,0.f,0.f), a01 = a00, a10 = a00, a11 = a00;
            #pragma unroll 4
            for (int k = k0; k < k0 + 8; ++k) {
                half8 hv = WhH[k * 16 + cg];
                float4 lo, hi; unpack8(hv, lo, hi);
                float x0 = hc2[0][k], x1 = hc2[1][k];
                fma4(a00, lo, x0); fma4(a01, hi, x0);
                fma4(a10, lo, x1); fma4(a11, hi, x1);
            }
            float* sp = scr + ks * 256 + cg * 8;
            *(float4*)(sp      ) = a00; *(float4*)(sp +   4) = a01;
            *(float4*)(sp + 128) = a10; *(float4*)(sp + 132) = a11;
        }
        __syncthreads();
        // P1b: combine 32
        if (tid < 256) {
            int j = tid & 127, r = tid >> 7;
            const float* sp = scr + r * 128 + j;
            float v = 0.f;
            #pragma unroll
            for (int ks = 0; ks < 32; ++ks) v += sp[ks * 256];
            qv[r][j] = v;
        }
        __syncthreads();

        // P2: scores sb[r][tp] = sum_h tanh(q[r][h] + wx[b][tp][h]) * Vw[h] + Vb
        for (int task = tid; task < 2 * TE; task += 512) {
            int r = (task >= TE) ? 1 : 0;
            int tp = task - r * TE;
            const half8* wxr = wx8 + ((size_t)(b0 + r) * TE + tp) * 16;
            float acc = Vb;
            #pragma unroll 4
            for (int kk = 0; kk < 16; ++kk) {
                half8 hv = wxr[kk];
                float4 lo, hi; unpack8(hv, lo, hi);
                int j = kk * 8;
                float4 q0 = *(const float4*)&qv[r][j], q1 = *(const float4*)&qv[r][j + 4];
                float4 v0 = *(const float4*)&Vw[j],    v1 = *(const float4*)&Vw[j + 4];
                acc += tanh_fast(q0.x + lo.x) * v0.x + tanh_fast(q0.y + lo.y) * v0.y
                     + tanh_fast(q0.z + lo.z) * v0.z + tanh_fast(q0.w + lo.w) * v0.w;
                acc += tanh_fast(q1.x + hi.x) * v1.x + tanh_fast(q1.y + hi.y) * v1.y
                     + tanh_fast(q1.z + hi.z) * v1.z + tanh_fast(q1.w + hi.w) * v1.w;
            }
            sb[r][tp] = acc;
        }
        __syncthreads();

        // P3: dec_in partials over tp chunks of 21  (thread = (cg32 x 4cols, r2, ts8))
        {
            int ts = tid >> 6, r = (tid >> 5) & 1, cg = tid & 31;
            int t0 = ts * 21;
            float4 a = make_float4(0.f, 0.f, 0.f, 0.f);
            #pragma unroll 3
            for (int tp = t0; tp < t0 + 21; ++tp) {
                float s = sb[r][tp];
                half4 m = mid4[((size_t)(b0 + r) * TE + tp) * 32 + cg];
                float4 mf;
                mf.x = (float)m[0]; mf.y = (float)m[1]; mf.z = (float)m[2]; mf.w = (float)m[3];
                fma4(a, mf, s);
            }
            *(float4*)&dinp[ts][r][cg * 4] = a;
        }
        __syncthreads();
        // P3b: combine into qv (reused as dec_in)
        if (tid < 256) {
            int j = tid & 127, r = tid >> 7;
            qv[r][j] = ((dinp[0][r][j] + dinp[1][r][j]) + (dinp[2][r][j] + dinp[3][r][j]))
                     + ((dinp[4][r][j] + dinp[5][r][j]) + (dinp[6][r][j] + dinp[7][r][j]));
        }
        __syncthreads();

        // P4: gate partials = dec_in@dWih + hi@dWhh  (thread = (cg64 x 8cols, ks8), both rows)
        {
            int cg = tid & 63, ks = tid >> 6;
            int kb = ks * 16;
            float4 a00 = make_float4(0.f,0.f,0.f,0.f), a01 = a00, a10 = a00, a11 = a00;
            #pragma unroll 4
            for (int k = kb; k < kb + 16; ++k) {
                half8 hv = dWih[k * 64 + cg];
                float4 lo, hi; unpack8(hv, lo, hi);
                float x0 = qv[0][k], x1 = qv[1][k];
                fma4(a00, lo, x0); fma4(a01, hi, x0);
                fma4(a10, lo, x1); fma4(a11, hi, x1);
            }
            #pragma unroll 4
            for (int k = kb; k < kb + 16; ++k) {
                half8 hv = dWhh[k * 64 + cg];
                float4 lo, hi; unpack8(hv, lo, hi);
                float x0 = hc2[0][k], x1 = hc2[1][k];
                fma4(a00, lo, x0); fma4(a01, hi, x0);
                fma4(a10, lo, x1); fma4(a11, hi, x1);
            }
            float* sp = scr + ks * 1024 + cg * 8;
            *(float4*)(sp      ) = a00; *(float4*)(sp +   4) = a01;
            *(float4*)(sp + 512) = a10; *(float4*)(sp + 516) = a11;
        }
        __syncthreads();

        // P5: combine 8 + LSTM update
        if (tid < 256) {
            int j = tid & 127, r = tid >> 7;
            const float* sp = scr + r * 512;
            float gi = bD[j], gf = bD[j + 128], gg = bD[j + 256], go = bD[j + 384];
            #pragma unroll
            for (int ks = 0; ks < 8; ++ks) {
                const float* p = sp + ks * 1024;
                gi += p[j]; gf += p[j + 128]; gg += p[j + 256]; go += p[j + 384];
            }
            float c = sigm(gf) * hc2[r][H_ + j] + sigm(gi) * tanh_fast(gg);
            float h = sigm(go) * tanh_fast(c);
            hc2[r][H_ + j] = c; hc2[r][j] = h;
        }
        __syncthreads();

        // P6: out[b][td] = h . reg_w + reg_b  (no trailing barrier: next P1 writes scr,
        // last read at P5 before its barrier; hc2 only read by P6 and next P1)
        if (tid < 128) {
            int r = tid >> 6, lane = tid & 63;
            float v = hc2[r][lane] * rw[lane] + hc2[r][lane + 64] * rw[lane + 64];
            for (int off = 32; off > 0; off >>= 1) v += __shfl_xor(v, off, 64);
            if (lane == 0) out[(b0 + r) * TD + td] = v + rb;
        }
    }
}

extern "C" void kernel_launch(void* const* d_in, const int* in_sizes, int n_in,
                              void* d_out, int out_size, void* d_ws, size_t ws_size,
                              hipStream_t stream)
{
    (void)in_sizes; (void)n_in; (void)out_size;
    if (ws_size < (size_t)WS_FLOATS * sizeof(float)) return;

    const float* x_all = (const float*)d_in[0];
    const float* Wi_b  = (const float*)d_in[3];
    const float* Vd_b  = (const float*)d_in[6];
    const float* Wx_b  = (const float*)d_in[16];
    const float* V_w   = (const float*)d_in[18];
    const float* V_b   = (const float*)d_in[19];
    const float* reg_w = (const float*)d_in[24];
    const float* reg_b = (const float*)d_in[25];
    float* ws  = (float*)d_ws;
    float* out = (float*)d_out;

    PrepArgs pa{
        (const float*)d_in[4],  // We_w
        (const float*)d_in[2],  // Wi_w
        (const float*)d_in[5],  // Vd_w
        (const float*)d_in[7],  // enc_Wih
        (const float*)d_in[8],  // enc_Whh
        (const float*)d_in[9],  // enc_bih
        (const float*)d_in[10], // enc_bhh
        (const float*)d_in[11], // mid_Wih
        (const float*)d_in[12], // mid_Whh
        (const float*)d_in[13], // mid_bih
        (const float*)d_in[14], // mid_bhh
        (const float*)d_in[15], // Wx_w
        (const float*)d_in[17], // Wh_w
        (const float*)d_in[20], // dec_Wih
        (const float*)d_in[21], // dec_Whh
        (const float*)d_in[22], // dec_bih
        (const float*)d_in[23]  // dec_bhh
    };

    prep_kernel<<<56, 256, 0, stream>>>(pa, ws);
    enc_mid_kernel<<<256, 512, 0, stream>>>(x_all, Wi_b, Vd_b, Wx_b, ws);
    dec_kernel<<<512, 512, 0, stream>>>(V_w, V_b, reg_w, reg_b, ws, out);
}

// Round 10
// 2394.198 us; speedup vs baseline: 6.4181x; 1.1436x over previous
//
#include <hip/hip_runtime.h>

#define B_   1024
#define TE   168
#define TD   24
#define F_   64
#define H_   128
#define H2_  256
#define G_   512
#define KM_  320
#define KP_  160   // k-pairs for m1

// ---- workspace float offsets (half arrays reuse the same slots) ----
#define OFF_WMT    0          // half pairs [160][256]
#define OFF_VdT    40960      // float [128][64]
#define OFF_eWihT  49152      // half pairs [32][1024]
#define OFF_eWhhT  81920      // half pairs [64][1024]
#define OFF_mWihT  147456     // half pairs [64][1024]
#define OFF_mWhhT  212992     // half pairs [64][1024]
#define OFF_WxT    278528     // half pairs [64][256]
#define OFF_WhT    294912     // half pairs [128][256]
#define OFF_dWihT  327680     // half pairs [64][1024]
#define OFF_dWhhT  393216     // half pairs [64][1024]
#define OFF_ENCB   458752     // float [512]
#define OFF_MIDB   459264
#define OFF_DECB   459776
#define OFF_MID    460800                      // half [1024][168][128]
#define OFF_WX     (OFF_MID + B_*TE*H_)        // half [1024][168][128]
#define OFF_STH    (OFF_WX  + B_*TE*H_)        // float [1024][128]
#define OFF_STC    (OFF_STH + B_*H_)
#define WS_FLOATS  (OFF_STC + B_*H_)

typedef _Float16 h2 __attribute__((ext_vector_type(2)));
typedef _Float16 h8 __attribute__((ext_vector_type(8)));

__device__ __forceinline__ float fexp2(float x) { return __builtin_amdgcn_exp2f(x); }
__device__ __forceinline__ float frcp(float x)  { return __builtin_amdgcn_rcpf(x); }
#define LOG2E 1.4426950408889634f

__device__ __forceinline__ float sigm(float x) {
    return frcp(1.f + fexp2(-LOG2E * x));
}
__device__ __forceinline__ float tanh_fast(float x) {
    float e = fexp2(2.f * LOG2E * x);
    return 1.f - 2.f * frcp(e + 1.f);
}

__device__ __forceinline__ float fdot2(h2 a, h2 b, float c) {
#if __has_builtin(__builtin_amdgcn_fdot2)
    return __builtin_amdgcn_fdot2(a, b, c, false);
#else
    return c + (float)a[0] * (float)b[0] + (float)a[1] * (float)b[1];
#endif
}
__device__ __forceinline__ void fma4(float4& g, const float4 wv, const float s) {
    g.x = __builtin_fmaf(wv.x, s, g.x);
    g.y = __builtin_fmaf(wv.y, s, g.y);
    g.z = __builtin_fmaf(wv.z, s, g.z);
    g.w = __builtin_fmaf(wv.w, s, g.w);
}

#define SH(V,I)  __builtin_shufflevector(V, V, 2*(I), 2*(I)+1)
#define H2X(F)   __builtin_bit_cast(h2, F)
#define SL(CG)   (4*((CG) + ((CG)>>3)))   // bank-optimal lane->slot swizzle

// one k-pair: weights = 2 half8 (8 cols as half2 pairs), acts = 4 rows of half2
#define DPAIR(LOV, HIV, ARV) { \
    h2 c0=SH(LOV,0), c1=SH(LOV,1), c2=SH(LOV,2), c3=SH(LOV,3); \
    h2 c4=SH(HIV,0), c5=SH(HIV,1), c6=SH(HIV,2), c7=SH(HIV,3); \
    h2 r0=H2X(ARV.x), r1=H2X(ARV.y), r2=H2X(ARV.z), r3=H2X(ARV.w); \
    a00.x=fdot2(r0,c0,a00.x); a00.y=fdot2(r0,c1,a00.y); a00.z=fdot2(r0,c2,a00.z); a00.w=fdot2(r0,c3,a00.w); \
    a01.x=fdot2(r0,c4,a01.x); a01.y=fdot2(r0,c5,a01.y); a01.z=fdot2(r0,c6,a01.z); a01.w=fdot2(r0,c7,a01.w); \
    a10.x=fdot2(r1,c0,a10.x); a10.y=fdot2(r1,c1,a10.y); a10.z=fdot2(r1,c2,a10.z); a10.w=fdot2(r1,c3,a10.w); \
    a11.x=fdot2(r1,c4,a11.x); a11.y=fdot2(r1,c5,a11.y); a11.z=fdot2(r1,c6,a11.z); a11.w=fdot2(r1,c7,a11.w); \
    a20.x=fdot2(r2,c0,a20.x); a20.y=fdot2(r2,c1,a20.y); a20.z=fdot2(r2,c2,a20.z); a20.w=fdot2(r2,c3,a20.w); \
    a21.x=fdot2(r2,c4,a21.x); a21.y=fdot2(r2,c5,a21.y); a21.z=fdot2(r2,c6,a21.z); a21.w=fdot2(r2,c7,a21.w); \
    a30.x=fdot2(r3,c0,a30.x); a30.y=fdot2(r3,c1,a30.y); a30.z=fdot2(r3,c2,a30.z); a30.w=fdot2(r3,c3,a30.w); \
    a31.x=fdot2(r3,c4,a31.x); a31.y=fdot2(r3,c5,a31.y); a31.z=fdot2(r3,c6,a31.z); a31.w=fdot2(r3,c7,a31.w); \
}
// 2-row variant (decoder)
#define DPAIR2(LOV, HIV, R0, R1) { \
    h2 c0=SH(LOV,0), c1=SH(LOV,1), c2=SH(LOV,2), c3=SH(LOV,3); \
    h2 c4=SH(HIV,0), c5=SH(HIV,1), c6=SH(HIV,2), c7=SH(HIV,3); \
    a00.x=fdot2(R0,c0,a00.x); a00.y=fdot2(R0,c1,a00.y); a00.z=fdot2(R0,c2,a00.z); a00.w=fdot2(R0,c3,a00.w); \
    a01.x=fdot2(R0,c4,a01.x); a01.y=fdot2(R0,c5,a01.y); a01.z=fdot2(R0,c6,a01.z); a01.w=fdot2(R0,c7,a01.w); \
    a10.x=fdot2(R1,c0,a10.x); a10.y=fdot2(R1,c1,a10.y); a10.z=fdot2(R1,c2,a10.z); a10.w=fdot2(R1,c3,a10.w); \
    a11.x=fdot2(R1,c4,a11.x); a11.y=fdot2(R1,c5,a11.y); a11.z=fdot2(R1,c6,a11.z); a11.w=fdot2(R1,c7,a11.w); \
}

// fp32 4-k group (VdT only)
#define GRP4(WT, STRIDE, CGV, KK, A0, A1, A2, A3)                         \
    {                                                                     \
        float4 wv0 = WT[(KK + 0) * STRIDE + CGV];                         \
        float4 wv1 = WT[(KK + 1) * STRIDE + CGV];                         \
        float4 wv2 = WT[(KK + 2) * STRIDE + CGV];                         \
        float4 wv3 = WT[(KK + 3) * STRIDE + CGV];                         \
        float4 xv0 = *(const float4*)&A0[KK];                             \
        float4 xv1 = *(const float4*)&A1[KK];                             \
        float4 xv2 = *(const float4*)&A2[KK];                             \
        float4 xv3 = *(const float4*)&A3[KK];                             \
        fma4(a0, wv0, xv0.x); fma4(a0, wv1, xv0.y); fma4(a0, wv2, xv0.z); fma4(a0, wv3, xv0.w); \
        fma4(a1, wv0, xv1.x); fma4(a1, wv1, xv1.y); fma4(a1, wv2, xv1.z); fma4(a1, wv3, xv1.w); \
        fma4(a2, wv0, xv2.x); fma4(a2, wv1, xv2.y); fma4(a2, wv2, xv2.z); fma4(a2, wv3, xv2.w); \
        fma4(a3, wv0, xv3.x); fma4(a3, wv1, xv3.y); fma4(a3, wv2, xv3.z); fma4(a3, wv3, xv3.w); \
    }

// ---------------- prep: transpose + pack k-pairs (fp16), sum bias pairs ----------------
struct PrepArgs {
    const float *We, *Wi, *Vd, *eWih, *eWhh, *eBih, *eBhh,
                *mWih, *mWhh, *mBih, *mBhh, *Wx, *Wh, *dWih, *dWhh, *dBih, *dBhh;
};

__global__ void prep_kernel(PrepArgs a, float* __restrict__ ws) {
    int sec  = blockIdx.x >> 2;
    int base = (blockIdx.x & 3) * blockDim.x + threadIdx.x;
    const int stride = blockDim.x * 4;
    const float* src = nullptr; int R = 0, C = 0, off = 0, hoffe = 0, ishalf = 1;
    switch (sec) {
        case 0:  src = a.We;   R = 128; C = 256; off = OFF_WMT;   hoffe = 0;     break;
        case 1:  src = a.Wi;   R = 128; C = 64;  off = OFF_WMT;   hoffe = 32768; break;
        case 2:  src = a.Vd;   R = 64;  C = 128; off = OFF_VdT;   ishalf = 0;    break;
        case 3:  src = a.eWih; R = 512; C = 64;  off = OFF_eWihT; break;
        case 4:  src = a.eWhh; R = 512; C = 128; off = OFF_eWhhT; break;
        case 5:  src = a.mWih; R = 512; C = 128; off = OFF_mWihT; break;
        case 6:  src = a.mWhh; R = 512; C = 128; off = OFF_mWhhT; break;
        case 7:  src = a.Wx;   R = 128; C = 128; off = OFF_WxT;   break;
        case 8:  src = a.Wh;   R = 128; C = 256; off = OFF_WhT;   break;
        case 9:  src = a.dWih; R = 512; C = 128; off = OFF_dWihT; break;
        case 10: src = a.dWhh; R = 512; C = 128; off = OFF_dWhhT; break;
        case 11: for (int i = base; i < 512; i += stride) ws[OFF_ENCB + i] = a.eBih[i] + a.eBhh[i]; return;
        case 12: for (int i = base; i < 512; i += stride) ws[OFF_MIDB + i] = a.mBih[i] + a.mBhh[i]; return;
        case 13: for (int i = base; i < 512; i += stride) ws[OFF_DECB + i] = a.dBih[i] + a.dBhh[i]; return;
        default: return;
    }
    int n = R * C;
    if (ishalf) {
        // pack pairs: dst[(k>>1)*2N + 2n + (k&1)] with K=C (src col), N=R (src row)
        _Float16* hd = (_Float16*)(ws + off) + hoffe;
        for (int o = base; o < n; o += stride) {
            int r = o % R, c = o / R;   // r = n (dst col), c = k
            hd[(c >> 1) * 2 * R + 2 * r + (c & 1)] = (_Float16)src[r * C + c];
        }
    } else {
        int rmask = R - 1, rshift = 6;  // Vd: R=64
        for (int o = base; o < n; o += stride) {
            int r = o & rmask, c = o >> rshift;
            ws[off + o] = src[r * C + c];
        }
    }
}

// ---------------- persistent encoder + mid LSTM: 256 blocks x 512 thr, 4 rows/block ----------------
__global__ __launch_bounds__(512, 1) void enc_mid_kernel(
    const float* __restrict__ x_all,
    const float* __restrict__ Wi_b,
    const float* __restrict__ Vd_b,
    const float* __restrict__ Wx_b,
    float* __restrict__ ws)
{
    __shared__ __align__(16) float scratch[18432];   // 72KB partials (time-disjoint)
    __shared__ __align__(16) h2 hcxH[KP_][4];        // pairs: h(0..63) | c(64..127) | x(128..159)
    __shared__ __align__(16) h2 hmH[64][4];          // mid h pairs
    __shared__ __align__(16) float cE[4][H_];        // enc c fp32 master
    __shared__ __align__(16) float cM[4][H_];        // mid c fp32 master
    __shared__ __align__(16) float xf[4][F_];        // current x fp32
    __shared__ __align__(16) float xnext[4][F_];
    __shared__ __align__(16) float av[4][H_];
    __shared__ __align__(16) h2 xinH[32][4];
    __shared__ float bWi[H_], bVd[F_], bWx[H_], bE[G_], bM[G_];

    const int tid = threadIdx.x;
    const int b0  = blockIdx.x * 4;

    for (int i = tid; i < 640; i += 512) ((float*)hcxH)[i] = 0.f;
    if (tid < 256) ((float*)hmH)[tid] = 0.f;
    ((float*)cE)[tid] = 0.f; ((float*)cM)[tid] = 0.f;
    if (tid < H_) { bWi[tid] = Wi_b[tid]; bWx[tid] = Wx_b[tid]; }
    if (tid < F_) bVd[tid] = Vd_b[tid];
    bE[tid] = ws[OFF_ENCB + tid];
    bM[tid] = ws[OFF_MIDB + tid];
    if (tid < 256) {  // x for t=0
        int r = tid >> 6, f = tid & 63;
        float v = x_all[((b0 + r) * TE + 0) * F_ + f];
        xf[r][f] = v;
        ((_Float16*)&hcxH[128 + (f >> 1)][r])[f & 1] = (_Float16)v;
    }
    __syncthreads();

    const h8*     WmH2  = (const h8*)(ws + OFF_WMT);     // [160 pairs][32]
    const float4* VdT4  = (const float4*)(ws + OFF_VdT); // [128][16] f4
    const h8*     eWih2 = (const h8*)(ws + OFF_eWihT);   // [32 pairs][128]
    const h8*     eWhh2 = (const h8*)(ws + OFF_eWhhT);   // [64 pairs][128]
    const h8*     mWih2 = (const h8*)(ws + OFF_mWihT);   // [64 pairs][128]
    const h8*     mWhh2 = (const h8*)(ws + OFF_mWhhT);   // [64 pairs][128]
    const h8*     WxH2  = (const h8*)(ws + OFF_WxT);     // [64 pairs][32]
    _Float16* midH = (_Float16*)(ws + OFF_MID);
    _Float16* wxH  = (_Float16*)(ws + OFF_WX);

    for (int t = 0; t < TE; ++t) {
        // ---- P1: m1 partials = [h|c|x] @ WmT  (thread = (cg16 x 8cols, ks32), 5 pairs each)
        {
            int cg = tid & 15, ks = tid >> 4;
            int p0 = ks * 5;
            float4 a00 = make_float4(0.f,0.f,0.f,0.f), a01 = a00, a10 = a00, a11 = a00,
                   a20 = a00, a21 = a00, a30 = a00, a31 = a00;
            #pragma unroll
            for (int i = 0; i < 5; ++i) {
                h8 lo = WmH2[(p0 + i) * 32 + cg * 2];
                h8 hi = WmH2[(p0 + i) * 32 + cg * 2 + 1];
                float4 ar = *(const float4*)&hcxH[p0 + i][0];
                DPAIR(lo, hi, ar);
            }
            int sl = SL(cg);
            float* sp = scratch + ks * 576;
            *(float4*)(sp +       sl) = a00; *(float4*)(sp +  72 + sl) = a01;
            *(float4*)(sp + 144 + sl) = a10; *(float4*)(sp + 216 + sl) = a11;
            *(float4*)(sp + 288 + sl) = a20; *(float4*)(sp + 360 + sl) = a21;
            *(float4*)(sp + 432 + sl) = a30; *(float4*)(sp + 504 + sl) = a31;
        }
        __syncthreads();
        // P1c: combine 32 + bias + tanh -> av
        {
            int j = tid & 127, r = tid >> 7;
            int e = j & 7, cgj = j >> 3;
            int idx = r * 144 + ((e < 4) ? SL(cgj) + e : 72 + SL(cgj) + (e - 4));
            float v = bWi[j];
            #pragma unroll
            for (int ks = 0; ks < 32; ++ks) v += scratch[ks * 576 + idx];
            av[r][j] = tanh_fast(v);
        }
        __syncthreads();

        // ---- P3a: s partials = av @ VdT (fp32, thread = (cg16 x 4cols, ks32), 4 k each)
        {
            int cg = tid & 15, ks = tid >> 4;
            int k0 = ks * 4;
            float4 a0 = make_float4(0.f,0.f,0.f,0.f), a1 = a0, a2 = a0, a3 = a0;
            GRP4(VdT4, 16, cg, k0, av[0], av[1], av[2], av[3]);
            float* sp = scratch + ks * 256 + cg * 4;
            *(float4*)(sp      ) = a0;
            *(float4*)(sp +  64) = a1;
            *(float4*)(sp + 128) = a2;
            *(float4*)(sp + 192) = a3;
        }
        __syncthreads();
        // P3b: combine 32 + softmax over 64 -> xinH; waves 4-7 prefetch x_{t+1}
        if (tid < 256) {
            int j = tid & 63, r = tid >> 6;
            const float* sp = scratch + r * 64 + j;
            float acc = bVd[j];
            #pragma unroll
            for (int ks = 0; ks < 32; ++ks) acc += sp[ks * 256];
            float m = acc;
            for (int off = 32; off > 0; off >>= 1) m = fmaxf(m, __shfl_xor(m, off, 64));
            float e = fexp2((acc - m) * LOG2E);
            float ssum = e;
            for (int off = 32; off > 0; off >>= 1) ssum += __shfl_xor(ssum, off, 64);
            float v = xf[r][j] * e * frcp(ssum);
            ((_Float16*)&xinH[j >> 1][r])[j & 1] = (_Float16)v;
        } else if (t + 1 < TE) {
            int q = tid - 256, r = q >> 6, f = q & 63;
            xnext[r][f] = x_all[((b0 + r) * TE + (t + 1)) * F_ + f];
        }
        __syncthreads();

        // ---- P4: enc gate partials = xin@eWih (32 pairs) + h@eWhh (64 pairs)  (cg64, ks8)
        {
            int cg = tid & 63, ks = tid >> 6;
            float4 a00 = make_float4(0.f,0.f,0.f,0.f), a01 = a00, a10 = a00, a11 = a00,
                   a20 = a00, a21 = a00, a30 = a00, a31 = a00;
            int pa = ks * 4;
            #pragma unroll
            for (int i = 0; i < 4; ++i) {
                h8 lo = eWih2[(pa + i) * 128 + cg * 2];
                h8 hi = eWih2[(pa + i) * 128 + cg * 2 + 1];
                float4 ar = *(const float4*)&xinH[pa + i][0];
                DPAIR(lo, hi, ar);
            }
            int pb = ks * 8;
            #pragma unroll 4
            for (int i = 0; i < 8; ++i) {
                h8 lo = eWhh2[(pb + i) * 128 + cg * 2];
                h8 hi = eWhh2[(pb + i) * 128 + cg * 2 + 1];
                float4 ar = *(const float4*)&hcxH[pb + i][0];
                DPAIR(lo, hi, ar);
            }
            int sl = SL(cg);
            float* sp = scratch + ks * 2304;
            *(float4*)(sp +        sl) = a00; *(float4*)(sp +  288 + sl) = a01;
            *(float4*)(sp +  576 + sl) = a10; *(float4*)(sp +  864 + sl) = a11;
            *(float4*)(sp + 1152 + sl) = a20; *(float4*)(sp + 1440 + sl) = a21;
            *(float4*)(sp + 1728 + sl) = a30; *(float4*)(sp + 2016 + sl) = a31;
        }
        __syncthreads();
        // P4c: combine 8/gate + enc LSTM cell; threads 0-255 install prefetched x
        {
            int j = tid & 127, r = tid >> 7;
            int e = j & 7, cgj = j >> 3;
            int i0, i1, i2, i3;
            {
                int c0 = cgj, c1 = 16 + cgj, c2 = 32 + cgj, c3 = 48 + cgj;
                i0 = (e < 4) ? SL(c0) + e : 288 + SL(c0) + (e - 4);
                i1 = (e < 4) ? SL(c1) + e : 288 + SL(c1) + (e - 4);
                i2 = (e < 4) ? SL(c2) + e : 288 + SL(c2) + (e - 4);
                i3 = (e < 4) ? SL(c3) + e : 288 + SL(c3) + (e - 4);
            }
            const float* sp = scratch + r * 576;
            float gi = bE[j], gf = bE[j + 128], gg = bE[j + 256], go = bE[j + 384];
            #pragma unroll
            for (int ks = 0; ks < 8; ++ks) {
                const float* p = sp + ks * 2304;
                gi += p[i0]; gf += p[i1]; gg += p[i2]; go += p[i3];
            }
            float c = sigm(gf) * cE[r][j] + sigm(gi) * tanh_fast(gg);
            float h = sigm(go) * tanh_fast(c);
            cE[r][j] = c;
            ((_Float16*)&hcxH[(j >> 1)][r])[j & 1]      = (_Float16)h;
            ((_Float16*)&hcxH[64 + (j >> 1)][r])[j & 1] = (_Float16)c;
            if (tid < 256 && t + 1 < TE) {
                int rr = tid >> 6, f = tid & 63;
                float v = xnext[rr][f];
                xf[rr][f] = v;
                ((_Float16*)&hcxH[128 + (f >> 1)][rr])[f & 1] = (_Float16)v;
            }
        }
        __syncthreads();

        // ---- P6: mid gate partials = h_enc@mWih + h_mid@mWhh  (64+64 pairs, cg64, ks8)
        {
            int cg = tid & 63, ks = tid >> 6;
            float4 a00 = make_float4(0.f,0.f,0.f,0.f), a01 = a00, a10 = a00, a11 = a00,
                   a20 = a00, a21 = a00, a30 = a00, a31 = a00;
            int pb = ks * 8;
            #pragma unroll 4
            for (int i = 0; i < 8; ++i) {
                h8 lo = mWih2[(pb + i) * 128 + cg * 2];
                h8 hi = mWih2[(pb + i) * 128 + cg * 2 + 1];
                float4 ar = *(const float4*)&hcxH[pb + i][0];
                DPAIR(lo, hi, ar);
            }
            #pragma unroll 4
            for (int i = 0; i < 8; ++i) {
                h8 lo = mWhh2[(pb + i) * 128 + cg * 2];
                h8 hi = mWhh2[(pb + i) * 128 + cg * 2 + 1];
                float4 ar = *(const float4*)&hmH[pb + i][0];
                DPAIR(lo, hi, ar);
            }
            int sl = SL(cg);
            float* sp = scratch + ks * 2304;
            *(float4*)(sp +        sl) = a00; *(float4*)(sp +  288 + sl) = a01;
            *(float4*)(sp +  576 + sl) = a10; *(float4*)(sp +  864 + sl) = a11;
            *(float4*)(sp + 1152 + sl) = a20; *(float4*)(sp + 1440 + sl) = a21;
            *(float4*)(sp + 1728 + sl) = a30; *(float4*)(sp + 2016 + sl) = a31;
        }
        __syncthreads();
        // P6c: combine + mid LSTM cell + store mid_out (fp16)
        {
            int j = tid & 127, r = tid >> 7;
            int e = j & 7, cgj = j >> 3;
            int i0, i1, i2, i3;
            {
                int c0 = cgj, c1 = 16 + cgj, c2 = 32 + cgj, c3 = 48 + cgj;
                i0 = (e < 4) ? SL(c0) + e : 288 + SL(c0) + (e - 4);
                i1 = (e < 4) ? SL(c1) + e : 288 + SL(c1) + (e - 4);
                i2 = (e < 4) ? SL(c2) + e : 288 + SL(c2) + (e - 4);
                i3 = (e < 4) ? SL(c3) + e : 288 + SL(c3) + (e - 4);
            }
            const float* sp = scratch + r * 576;
            float gi = bM[j], gf = bM[j + 128], gg = bM[j + 256], go = bM[j + 384];
            #pragma unroll
            for (int ks = 0; ks < 8; ++ks) {
                const float* p = sp + ks * 2304;
                gi += p[i0]; gf += p[i1]; gg += p[i2]; go += p[i3];
            }
            float c = sigm(gf) * cM[r][j] + sigm(gi) * tanh_fast(gg);
            float h = sigm(go) * tanh_fast(c);
            cM[r][j] = c;
            ((_Float16*)&hmH[j >> 1][r])[j & 1] = (_Float16)h;
            midH[((size_t)(b0 + r) * TE + t) * H_ + j] = (_Float16)h;
        }
        __syncthreads();

        // ---- P8: wx partials = h_mid @ WxT  (cg16, ks32, 2 pairs each)
        {
            int cg = tid & 15, ks = tid >> 4;
            int p0 = ks * 2;
            float4 a00 = make_float4(0.f,0.f,0.f,0.f), a01 = a00, a10 = a00, a11 = a00,
                   a20 = a00, a21 = a00, a30 = a00, a31 = a00;
            #pragma unroll
            for (int i = 0; i < 2; ++i) {
                h8 lo = WxH2[(p0 + i) * 32 + cg * 2];
                h8 hi = WxH2[(p0 + i) * 32 + cg * 2 + 1];
                float4 ar = *(const float4*)&hmH[p0 + i][0];
                DPAIR(lo, hi, ar);
            }
            int sl = SL(cg);
            float* sp = scratch + ks * 576;
            *(float4*)(sp +       sl) = a00; *(float4*)(sp +  72 + sl) = a01;
            *(float4*)(sp + 144 + sl) = a10; *(float4*)(sp + 216 + sl) = a11;
            *(float4*)(sp + 288 + sl) = a20; *(float4*)(sp + 360 + sl) = a21;
            *(float4*)(sp + 432 + sl) = a30; *(float4*)(sp + 504 + sl) = a31;
        }
        __syncthreads();
        // P8c: combine + store wx (fp16)
        {
            int j = tid & 127, r = tid >> 7;
            int e = j & 7, cgj = j >> 3;
            int idx = r * 144 + ((e < 4) ? SL(cgj) + e : 72 + SL(cgj) + (e - 4));
            float v = bWx[j];
            #pragma unroll
            for (int ks = 0; ks < 32; ++ks) v += scratch[ks * 576 + idx];
            wxH[((size_t)(b0 + r) * TE + t) * H_ + j] = (_Float16)v;
        }
        __syncthreads();
    }

    {
        int j = tid & 127, r = tid >> 7;
        ws[OFF_STH + (b0 + r) * H_ + j] = (float)((_Float16*)&hmH[j >> 1][r])[j & 1];
        ws[OFF_STC + (b0 + r) * H_ + j] = cM[r][j];
    }
}

// ---------------- persistent decoder: 512 blocks x 512 thr, 2 rows/block ----------------
#define QP_ 132

__global__ __launch_bounds__(512, 2) void dec_kernel(
    const float* __restrict__ Vw_in,
    const float* __restrict__ Vb_in,
    const float* __restrict__ rw_in,
    const float* __restrict__ rb_in,
    const float* __restrict__ ws,
    float* __restrict__ out)
{
    __shared__ __align__(16) float scr[9216];        // 36KB partials
    __shared__ __align__(16) float hc2[2][H2_];
    __shared__ __align__(16) float qv[2][QP_];
    __shared__ __align__(16) float sb[2][TE];
    __shared__ __align__(16) float dinp[8][2][H_];
    __shared__ float bD[G_], Vw[H_], rw[H_];

    const int tid = threadIdx.x;
    const int b0  = blockIdx.x * 2;
    const float Vb = Vb_in[0], rb = rb_in[0];

    {
        int r = tid >> 8, c = tid & 255;
        hc2[r][c] = (c < H_) ? ws[OFF_STH + (b0 + r) * H_ + c]
                             : ws[OFF_STC + (b0 + r) * H_ + (c - H_)];
    }
    if (tid < H_) { Vw[tid] = Vw_in[tid]; rw[tid] = rw_in[tid]; }
    bD[tid] = ws[OFF_DECB + tid];
    __syncthreads();

    const h8* WhH2  = (const h8*)(ws + OFF_WhT);     // [128 pairs][32]
    const h8* dWih2 = (const h8*)(ws + OFF_dWihT);   // [64 pairs][128]
    const h8* dWhh2 = (const h8*)(ws + OFF_dWhhT);   // [64 pairs][128]
    const h8* wx8   = (const h8*)(ws + OFF_WX);
    typedef _Float16 h4 __attribute__((ext_vector_type(4)));
    const h4* mid4 = (const h4*)(ws + OFF_MID);

    for (int td = 0; td < TD; ++td) {
        // P1: q partials = [hi|ci]@WhT  (cg16 x 8cols, ks32, 4 pairs each, both rows)
        {
            int cg = tid & 15, ks = tid >> 4;
            int p0 = ks * 4;
            float4 a00 = make_float4(0.f,0.f,0.f,0.f), a01 = a00, a10 = a00, a11 = a00;
            #pragma unroll
            for (int i = 0; i < 4; ++i) {
                int p = p0 + i;
                h8 lo = WhH2[p * 32 + cg * 2];
                h8 hi = WhH2[p * 32 + cg * 2 + 1];
                h2 r0; r0[0] = (_Float16)hc2[0][2*p]; r0[1] = (_Float16)hc2[0][2*p+1];
                h2 r1; r1[0] = (_Float16)hc2[1][2*p]; r1[1] = (_Float16)hc2[1][2*p+1];
                DPAIR2(lo, hi, r0, r1);
            }
            int sl = SL(cg);
            float* sp = scr + ks * 288;
            *(float4*)(sp +       sl) = a00; *(float4*)(sp +  72 + sl) = a01;
            *(float4*)(sp + 144 + sl) = a10; *(float4*)(sp + 216 + sl) = a11;
        }
        __syncthreads();
        // P1b: combine 32
        if (tid < 256) {
            int j = tid & 127, r = tid >> 7;
            int e = j & 7, cgj = j >> 3;
            int idx = r * 144 + ((e < 4) ? SL(cgj) + e : 72 + SL(cgj) + (e - 4));
            float v = 0.f;
            #pragma unroll
            for (int ks = 0; ks < 32; ++ks) v += scr[ks * 288 + idx];
            qv[r][j] = v;
        }
        __syncthreads();

        // P2: scores
        for (int task = tid; task < 2 * TE; task += 512) {
            int r = (task >= TE) ? 1 : 0;
            int tp = task - r * TE;
            const h8* wxr = wx8 + ((size_t)(b0 + r) * TE + tp) * 16;
            float acc = Vb;
            #pragma unroll 4
            for (int kk = 0; kk < 16; ++kk) {
                h8 hv = wxr[kk];
                int j = kk * 8;
                float4 q0 = *(const float4*)&qv[r][j], q1 = *(const float4*)&qv[r][j + 4];
                float4 v0 = *(const float4*)&Vw[j],    v1 = *(const float4*)&Vw[j + 4];
                acc += tanh_fast(q0.x + (float)hv[0]) * v0.x + tanh_fast(q0.y + (float)hv[1]) * v0.y
                     + tanh_fast(q0.z + (float)hv[2]) * v0.z + tanh_fast(q0.w + (float)hv[3]) * v0.w;
                acc += tanh_fast(q1.x + (float)hv[4]) * v1.x + tanh_fast(q1.y + (float)hv[5]) * v1.y
                     + tanh_fast(q1.z + (float)hv[6]) * v1.z + tanh_fast(q1.w + (float)hv[7]) * v1.w;
            }
            sb[r][tp] = acc;
        }
        __syncthreads();

        // P3: dec_in partials over tp chunks of 21
        {
            int ts = tid >> 6, r = (tid >> 5) & 1, cg = tid & 31;
            int t0 = ts * 21;
            float4 a = make_float4(0.f, 0.f, 0.f, 0.f);
            #pragma unroll 3
            for (int tp = t0; tp < t0 + 21; ++tp) {
                float s = sb[r][tp];
                h4 m = mid4[((size_t)(b0 + r) * TE + tp) * 32 + cg];
                float4 mf;
                mf.x = (float)m[0]; mf.y = (float)m[1]; mf.z = (float)m[2]; mf.w = (float)m[3];
                fma4(a, mf, s);
            }
            *(float4*)&dinp[ts][r][cg * 4] = a;
        }
        __syncthreads();
        // P3b: combine into qv (dec_in)
        if (tid < 256) {
            int j = tid & 127, r = tid >> 7;
            qv[r][j] = ((dinp[0][r][j] + dinp[1][r][j]) + (dinp[2][r][j] + dinp[3][r][j]))
                     + ((dinp[4][r][j] + dinp[5][r][j]) + (dinp[6][r][j] + dinp[7][r][j]));
        }
        __syncthreads();

        // P4: gate partials = dec_in@dWih + hi@dWhh  (cg64, ks8, 8+8 pairs)
        {
            int cg = tid & 63, ks = tid >> 6;
            int p0 = ks * 8;
            float4 a00 = make_float4(0.f,0.f,0.f,0.f), a01 = a00, a10 = a00, a11 = a00;
            #pragma unroll 4
            for (int i = 0; i < 8; ++i) {
                int p = p0 + i;
                h8 lo = dWih2[p * 128 + cg * 2];
                h8 hi = dWih2[p * 128 + cg * 2 + 1];
                h2 r0; r0[0] = (_Float16)qv[0][2*p]; r0[1] = (_Float16)qv[0][2*p+1];
                h2 r1; r1[0] = (_Float16)qv[1][2*p]; r1[1] = (_Float16)qv[1][2*p+1];
                DPAIR2(lo, hi, r0, r1);
            }
            #pragma unroll 4
            for (int i = 0; i < 8; ++i) {
                int p = p0 + i;
                h8 lo = dWhh2[p * 128 + cg * 2];
                h8 hi = dWhh2[p * 128 + cg * 2 + 1];
                h2 r0; r0[0] = (_Float16)hc2[0][2*p]; r0[1] = (_Float16)hc2[0][2*p+1];
                h2 r1; r1[0] = (_Float16)hc2[1][2*p]; r1[1] = (_Float16)hc2[1][2*p+1];
                DPAIR2(lo, hi, r0, r1);
            }
            int sl = SL(cg);
            float* sp = scr + ks * 1152;
            *(float4*)(sp +       sl) = a00; *(float4*)(sp + 288 + sl) = a01;
            *(float4*)(sp + 576 + sl) = a10; *(float4*)(sp + 864 + sl) = a11;
        }
        __syncthreads();

        // P5: combine 8 + LSTM update
        if (tid < 256) {
            int j = tid & 127, r = tid >> 7;
            int e = j & 7, cgj = j >> 3;
            int i0, i1, i2, i3;
            {
                int c0 = cgj, c1 = 16 + cgj, c2 = 32 + cgj, c3 = 48 + cgj;
                i0 = (e < 4) ? SL(c0) + e : 288 + SL(c0) + (e - 4);
                i1 = (e < 4) ? SL(c1) + e : 288 + SL(c1) + (e - 4);
                i2 = (e < 4) ? SL(c2) + e : 288 + SL(c2) + (e - 4);
                i3 = (e < 4) ? SL(c3) + e : 288 + SL(c3) + (e - 4);
            }
            const float* sp = scr + r * 576;
            float gi = bD[j], gf = bD[j + 128], gg = bD[j + 256], go = bD[j + 384];
            #pragma unroll
            for (int ks = 0; ks < 8; ++ks) {
                const float* p = sp + ks * 1152;
                gi += p[i0]; gf += p[i1]; gg += p[i2]; go += p[i3];
            }
            float c = sigm(gf) * hc2[r][H_ + j] + sigm(gi) * tanh_fast(gg);
            float h = sigm(go) * tanh_fast(c);
            hc2[r][H_ + j] = c; hc2[r][j] = h;
        }
        __syncthreads();

        // P6: output dot (no trailing barrier needed)
        if (tid < 128) {
            int r = tid >> 6, lane = tid & 63;
            float v = hc2[r][lane] * rw[lane] + hc2[r][lane + 64] * rw[lane + 64];
            for (int off = 32; off > 0; off >>= 1) v += __shfl_xor(v, off, 64);
            if (lane == 0) out[(b0 + r) * TD + td] = v + rb;
        }
    }
}

extern "C" void kernel_launch(void* const* d_in, const int* in_sizes, int n_in,
                              void* d_out, int out_size, void* d_ws, size_t ws_size,
                              hipStream_t stream)
{
    (void)in_sizes; (void)n_in; (void)out_size;
    if (ws_size < (size_t)WS_FLOATS * sizeof(float)) return;

    const float* x_all = (const float*)d_in[0];
    const float* Wi_b  = (const float*)d_in[3];
    const float* Vd_b  = (const float*)d_in[6];
    const float* Wx_b  = (const float*)d_in[16];
    const float* V_w   = (const float*)d_in[18];
    const float* V_b   = (const float*)d_in[19];
    const float* reg_w = (const float*)d_in[24];
    const float* reg_b = (const float*)d_in[25];
    float* ws  = (float*)d_ws;
    float* out = (float*)d_out;

    PrepArgs pa{
        (const float*)d_in[4],  // We_w
        (const float*)d_in[2],  // Wi_w
        (const float*)d_in[5],  // Vd_w
        (const float*)d_in[7],  // enc_Wih
        (const float*)d_in[8],  // enc_Whh
        (const float*)d_in[9],  // enc_bih
        (const float*)d_in[10], // enc_bhh
        (const float*)d_in[11], // mid_Wih
        (const float*)d_in[12], // mid_Whh
        (const float*)d_in[13], // mid_bih
        (const float*)d_in[14], // mid_bhh
        (const float*)d_in[15], // Wx_w
        (const float*)d_in[17], // Wh_w
        (const float*)d_in[20], // dec_Wih
        (const float*)d_in[21], // dec_Whh
        (const float*)d_in[22], // dec_bih
        (const float*)d_in[23]  // dec_bhh
    };

    prep_kernel<<<56, 256, 0, stream>>>(pa, ws);
    enc_mid_kernel<<<256, 512, 0, stream>>>(x_all, Wi_b, Vd_b, Wx_b, ws);
    dec_kernel<<<512, 512, 0, stream>>>(V_w, V_b, reg_w, reg_b, ws, out);
}